// Round 13
// baseline (274.078 us; speedup 1.0000x reference)
//
#include <hip/hip_runtime.h>
#include <stdint.h>

#define D_DIM 512

typedef __attribute__((ext_vector_type(8))) short bf16x8;
typedef __attribute__((ext_vector_type(4))) float f32x4;
typedef __attribute__((ext_vector_type(4))) short short4_t;
typedef __attribute__((ext_vector_type(4))) float float4_t;

__device__ __forceinline__ unsigned short f2bf(float f) {
  unsigned u = __float_as_uint(f);
  u += 0x7FFFu + ((u >> 16) & 1u);
  return (unsigned short)(u >> 16);
}

__device__ __forceinline__ float bf2f(unsigned short s) {
  return __uint_as_float(((unsigned)s) << 16);
}

__device__ __forceinline__ float tanh_fast(float x) {
  float e = __expf(2.0f * x);
  return 1.0f - 2.0f / (e + 1.0f);
}

#define GLOAD_LDS16(gsrc, ldst) \
  __builtin_amdgcn_global_load_lds((const __attribute__((address_space(1))) void*)(gsrc), \
                                   (__attribute__((address_space(3))) void*)(ldst), 16, 0, 0)

// ---------------- small utility kernels ----------------

__global__ void cvt_f32_bf16_k(const float* __restrict__ in, unsigned short* __restrict__ out, int n4) {
  int i = blockIdx.x * blockDim.x + threadIdx.x;
  if (i < n4) {
    float4_t v = ((const float4_t*)in)[i];
    short4_t s;
    s.x = (short)f2bf(v.x); s.y = (short)f2bf(v.y);
    s.z = (short)f2bf(v.z); s.w = (short)f2bf(v.w);
    ((short4_t*)out)[i] = s;
  }
}

__global__ void cvt3_f32_bf16_k(const float* __restrict__ a, const float* __restrict__ b,
                                const float* __restrict__ c, unsigned short* __restrict__ out,
                                int n4each) {
  int i = blockIdx.x * blockDim.x + threadIdx.x;
  if (i >= 3 * n4each) return;
  int sel = i / n4each, j = i - sel * n4each;
  const float* src = (sel == 0) ? a : (sel == 1) ? b : c;
  float4_t v = ((const float4_t*)src)[j];
  short4_t s;
  s.x = (short)f2bf(v.x); s.y = (short)f2bf(v.y);
  s.z = (short)f2bf(v.z); s.w = (short)f2bf(v.w);
  ((short4_t*)out)[i] = s;
}

__global__ void prep_cluster_k(const int* __restrict__ vn, const int* __restrict__ nid,
                               int* __restrict__ cl, int* __restrict__ counts, int B) {
  int i = blockIdx.x * blockDim.x + threadIdx.x;
  if (i < B) {
    int c = vn[2 * nid[i] + 1];
    cl[i] = c;
    atomicAdd(&counts[c], 1);
  }
}

__global__ void prefix_k(const int* __restrict__ counts, int* __restrict__ starts,
                         int* __restrict__ cursor, int C) {
  __shared__ int sh[1024];
  int t = threadIdx.x;
  int v = (t < C) ? counts[t] : 0;
  sh[t] = v;
  __syncthreads();
  for (int off = 1; off < 1024; off <<= 1) {
    int x = (t >= off) ? sh[t - off] : 0;
    __syncthreads();
    sh[t] += x;
    __syncthreads();
  }
  if (t < C) { int st = sh[t] - v; starts[t] = st; cursor[t] = st; }
  if (t == 1023) starts[C] = sh[1023];
}

__global__ void scatter_k(const int* __restrict__ cl, int* __restrict__ cursor,
                          int* __restrict__ order, int B) {
  int i = blockIdx.x * blockDim.x + threadIdx.x;
  if (i < B) {
    int pos = atomicAdd(&cursor[cl[i]], 1);
    order[pos] = i;
  }
}

__device__ __forceinline__ unsigned enc_f(float f) {
  unsigned u = __float_as_uint(f);
  return (u & 0x80000000u) ? ~u : (u | 0x80000000u);
}
__device__ __forceinline__ float dec_f(unsigned u) {
  return __uint_as_float((u & 0x80000000u) ? (u & 0x7FFFFFFFu) : ~u);
}

__global__ void seg_max_k(const float* __restrict__ score, const int* __restrict__ cl,
                          unsigned* __restrict__ smax, int B) {
  int i = blockIdx.x * blockDim.x + threadIdx.x;
  if (i < B) atomicMax(&smax[cl[i]], enc_f(score[i]));
}

__global__ void seg_expsum_k(const float* __restrict__ score, const int* __restrict__ cl,
                             const unsigned* __restrict__ smax, float* __restrict__ ev,
                             float* __restrict__ denom, int B) {
  int i = blockIdx.x * blockDim.x + threadIdx.x;
  if (i < B) {
    int c = cl[i];
    float x = __expf(score[i] - dec_f(smax[c]));
    ev[i] = x;
    atomicAdd(&denom[c], x);
  }
}

__global__ __launch_bounds__(256)
void ctx_k(const unsigned short* __restrict__ hbf, const float* __restrict__ ev,
           const int* __restrict__ order, const int* __restrict__ starts,
           const float* __restrict__ denom, float* __restrict__ ctx) {
  int c = blockIdx.x;
  int t = threadIdx.x;
  int s0 = starts[c], s1 = starts[c + 1];
  float a0 = 0.f, a1 = 0.f;
  int j = s0;
  for (; j + 3 < s1; j += 4) {
    int i0 = order[j], i1 = order[j + 1], i2 = order[j + 2], i3 = order[j + 3];
    float e0 = ev[i0], e1 = ev[i1], e2 = ev[i2], e3 = ev[i3];
    unsigned u0 = *(const unsigned*)(hbf + (size_t)i0 * D_DIM + t * 2);
    unsigned u1 = *(const unsigned*)(hbf + (size_t)i1 * D_DIM + t * 2);
    unsigned u2 = *(const unsigned*)(hbf + (size_t)i2 * D_DIM + t * 2);
    unsigned u3 = *(const unsigned*)(hbf + (size_t)i3 * D_DIM + t * 2);
    a0 += e0 * bf2f((unsigned short)u0) + e1 * bf2f((unsigned short)u1)
        + e2 * bf2f((unsigned short)u2) + e3 * bf2f((unsigned short)u3);
    a1 += e0 * bf2f((unsigned short)(u0 >> 16)) + e1 * bf2f((unsigned short)(u1 >> 16))
        + e2 * bf2f((unsigned short)(u2 >> 16)) + e3 * bf2f((unsigned short)(u3 >> 16));
  }
  for (; j < s1; ++j) {
    int i0 = order[j];
    float e0 = ev[i0];
    unsigned u0 = *(const unsigned*)(hbf + (size_t)i0 * D_DIM + t * 2);
    a0 += e0 * bf2f((unsigned short)u0);
    a1 += e0 * bf2f((unsigned short)(u0 >> 16));
  }
  float inv = 1.0f / denom[c];
  float2 r = make_float2(a0 * inv, a1 * inv);
  *(float2*)(&ctx[(size_t)c * D_DIM + t * 2]) = r;
}

// ====== FINE-PHASE 256x256 score GEMM: BK=32, 8 waves, 3 LDS slots ======
// R12 structure with the vmcnt-count race FIXED: the prologue must issue all
// 4 slices of tile 0 BEFORE any slice of tile 1, so that top-of-body vmcnt(4)
// (which waits for the OLDEST outstanding ops, m135) drains exactly tile kt.
// R12's interleaved prologue left tile 0's A1/B1 slices among the newest 4 ->
// body 0 read rows 128-255 before they landed (absmax 0.061).
// Schedule per K-tile kt: top {vmcnt(4); s_barrier} then 4 fine phases, each
// {ds_read 2 a-frags (+4 b at p0); issue 1 gload_lds slice of tile kt+2;
//  s_barrier; lgkmcnt(0); setprio(1) 8 MFMA setprio(0); s_barrier}.
// Tile kt+1's 4 slices stay in flight across the top wait (T4). Slot (kt+2)%3
// == (kt-1)%3 was fully read before body kt's top barrier -> write-safe.
// 8 waves of 128x64 (acc[8][4]); LDS 96KB slots + 5KB -> 1 block/CU.
// Swizzle slot^((row>>1)&3) (R9: 0 conflicts); gload_lds linear dst +
// pre-swizzled source (rule #21).
__global__ __launch_bounds__(512, 2)
void gemm256_phase_score_k(const unsigned short* __restrict__ Abf,
                           const unsigned short* __restrict__ Bw, int M,
                           const float* __restrict__ qb, const int* __restrict__ cl,
                           const float* __restrict__ Ws, float* __restrict__ out)
{
  // A slots: 3 x 16KB at [0, 49152); B slots: 3 x 16KB at [49152, 98304)
  __shared__ char ABmem[98304];
  __shared__ float red[256][4];
  __shared__ int clds[256];

  const int t = threadIdx.x;
  const int lane = t & 63;
  const int w = t >> 6;                  // 0..7
  const int wr = w >> 2, wc = w & 3;     // wave tile: rows wr*128, cols wc*64
  const int l15 = lane & 15, l4 = lane >> 4;

  // m204 bijective XCD-chunk swizzle
  int id;
  {
    int nwg = gridDim.x;
    int q = nwg >> 3, r = nwg & 7;
    int xcd = blockIdx.x & 7, pos = blockIdx.x >> 3;
    id = (xcd < r ? xcd * (q + 1) : r * (q + 1) + (xcd - r) * q) + pos;
  }
  const int n0 = (id & 1) * 256;         // N fastest: 2 siblings share A panel
  const int m0 = (id >> 1) * 256;

  // ---- staging: tile = 4 slices {A0,A1,B0,B1}; slice = 128 rows x 64B = 8KB
  // = 512 thr x 16B. Thread t covers row i*128 + w*16 + (lane>>2), slot lane&3;
  // source slot carries inverse swizzle ^((row>>1)&3).
  const unsigned short* srcA[2];
  const unsigned short* srcB[2];
  #pragma unroll
  for (int i = 0; i < 2; ++i) {
    int row = i * 128 + w * 16 + (lane >> 2);
    int ss = (lane & 3) ^ ((row >> 1) & 3);
    int ga = m0 + row; if (ga > M - 1) ga = M - 1;
    srcA[i] = Abf + (size_t)ga * 512 + ss * 8;
    srcB[i] = Bw + (size_t)(n0 + row) * 512 + ss * 8;
  }
  const int dstOff = w * 1024;           // + i*8192 + slot*16384 (+49152 for B)

  // fragment byte offsets within one 16KB slot
  int offA[8], offB[4];
  #pragma unroll
  for (int mi = 0; mi < 8; ++mi) {
    int row = wr * 128 + mi * 16 + l15;
    offA[mi] = row * 64 + ((l4 ^ ((row >> 1) & 3)) * 16);
  }
  #pragma unroll
  for (int ni = 0; ni < 4; ++ni) {
    int row = wc * 64 + ni * 16 + l15;
    offB[ni] = row * 64 + ((l4 ^ ((row >> 1) & 3)) * 16);
  }

  f32x4 acc[8][4];
  #pragma unroll
  for (int mi = 0; mi < 8; ++mi)
    #pragma unroll
    for (int ni = 0; ni < 4; ++ni)
      acc[mi][ni] = (f32x4){0.f, 0.f, 0.f, 0.f};

  // ---- prologue: stage T0 (ALL 4 slices) then T1 (ALL 4 slices) ----
  // Issue order is the vmcnt count order: tile-grouped, oldest = tile 0.
  #pragma unroll
  for (int i = 0; i < 2; ++i) {
    GLOAD_LDS16(srcA[i], ABmem + 0 * 16384 + i * 8192 + dstOff);
    GLOAD_LDS16(srcB[i], ABmem + 49152 + 0 * 16384 + i * 8192 + dstOff);
  }
  __builtin_amdgcn_sched_barrier(0);
  #pragma unroll
  for (int i = 0; i < 2; ++i) {
    GLOAD_LDS16(srcA[i] + 32, ABmem + 1 * 16384 + i * 8192 + dstOff);
    GLOAD_LDS16(srcB[i] + 32, ABmem + 49152 + 1 * 16384 + i * 8192 + dstOff);
  }
  __builtin_amdgcn_sched_barrier(0);

  #pragma unroll
  for (int kt = 0; kt < 16; ++kt) {
    const int st = kt % 3;
    const char* Aslot = ABmem + st * 16384;
    const char* Bslot = ABmem + 49152 + st * 16384;
    char* AslotN = ABmem + ((kt + 2) % 3) * 16384;
    char* BslotN = ABmem + 49152 + ((kt + 2) % 3) * 16384;

    // top of body: drain tile kt (its 4 slices are the oldest); keep kt+1 flying
    if (kt < 14) asm volatile("s_waitcnt vmcnt(4)" ::: "memory");
    else         asm volatile("s_waitcnt vmcnt(0)" ::: "memory");
    __builtin_amdgcn_sched_barrier(0);
    __builtin_amdgcn_s_barrier();
    __builtin_amdgcn_sched_barrier(0);

    bf16x8 bfr[4];
    #pragma unroll
    for (int p = 0; p < 4; ++p) {
      bf16x8 alo, ahi;
      if (p == 0) {
        #pragma unroll
        for (int ni = 0; ni < 4; ++ni)
          bfr[ni] = *(const bf16x8*)(Bslot + offB[ni]);
      }
      alo = *(const bf16x8*)(Aslot + offA[2 * p]);
      ahi = *(const bf16x8*)(Aslot + offA[2 * p + 1]);

      // issue exactly ONE slice of tile kt+2 into its (freed) slot
      if (kt < 14) {
        const int ka = (kt + 2) * 32;
        if (p < 2) GLOAD_LDS16(srcA[p] + ka, AslotN + p * 8192 + dstOff);
        else       GLOAD_LDS16(srcB[p - 2] + ka, BslotN + (p - 2) * 8192 + dstOff);
      }
      __builtin_amdgcn_sched_barrier(0);
      __builtin_amdgcn_s_barrier();
      asm volatile("s_waitcnt lgkmcnt(0)" ::: "memory");
      __builtin_amdgcn_sched_barrier(0);

      __builtin_amdgcn_s_setprio(1);
      #pragma unroll
      for (int ni = 0; ni < 4; ++ni) {
        acc[2 * p][ni]     = __builtin_amdgcn_mfma_f32_16x16x32_bf16(alo, bfr[ni], acc[2 * p][ni], 0, 0, 0);
        acc[2 * p + 1][ni] = __builtin_amdgcn_mfma_f32_16x16x32_bf16(ahi, bfr[ni], acc[2 * p + 1][ni], 0, 0, 0);
      }
      __builtin_amdgcn_s_setprio(0);
      __builtin_amdgcn_sched_barrier(0);
      __builtin_amdgcn_s_barrier();
      __builtin_amdgcn_sched_barrier(0);
    }
  }

  // ---- epilogue: fused additive-attention partial score over 256 cols ----
  if (t < 256) {
    int gm = m0 + t;
    clds[t] = cl[gm < M ? gm : M - 1];
  }
  __syncthreads();
  #pragma unroll
  for (int mi = 0; mi < 8; ++mi) {
    #pragma unroll
    for (int r = 0; r < 4; ++r) {
      int rowt = wr * 128 + mi * 16 + l4 * 4 + r;
      int c = clds[rowt];
      const float* qrow = &qb[(size_t)c * 512];
      float s = 0.f;
      #pragma unroll
      for (int ni = 0; ni < 4; ++ni) {
        int gcol = n0 + wc * 64 + ni * 16 + l15;
        float x = acc[mi][ni][r] + qrow[gcol];
        s += tanh_fast(x) * Ws[gcol];
      }
      s += __shfl_xor(s, 1);
      s += __shfl_xor(s, 2);
      s += __shfl_xor(s, 4);
      s += __shfl_xor(s, 8);
      if (l15 == 0) red[rowt][wc] = s;
    }
  }
  __syncthreads();
  if (t < 256) {
    int gm = m0 + t;
    if (gm < M) atomicAdd(&out[gm], red[t][0] + red[t][1] + red[t][2] + red[t][3]);
  }
}

// --- bf16 MFMA GEMM: 128x128 tile, BK=32 -- small GEMMs only ---
template<int EPI>
__global__ __launch_bounds__(256)
void gemm128_k(const unsigned short* __restrict__ Abf,
               const unsigned short* __restrict__ Bw, int M,
               const float* __restrict__ bias, float* __restrict__ out)
{
  __shared__ unsigned short As[2][128 * 32];
  __shared__ unsigned short Bs[2][128 * 32];

  const int t = threadIdx.x;
  const int lane = t & 63;
  const int w = t >> 6;
  const int wr = w >> 1, wc = w & 1;
  const int l15 = lane & 15, l4 = lane >> 4;

  const int nwg = gridDim.x;
  int id = blockIdx.x;
  if ((nwg & 7) == 0) id = (id & 7) * (nwg >> 3) + (id >> 3);
  const int n0 = (id & 3) * 128;
  const int m0 = (id >> 2) * 128;

  const int rin = lane >> 2;
  const int sl = lane & 3;

  const unsigned short* srcA[2];
  const unsigned short* srcB[2];
  int dstOff[2];
  #pragma unroll
  for (int c = 0; c < 2; ++c) {
    int chunk = w * 2 + c;
    int row = chunk * 16 + rin;
    int slot = sl ^ ((row >> 1) & 3);
    int ga = m0 + row; if (ga > M - 1) ga = M - 1;
    srcA[c] = Abf + (size_t)ga * 512 + slot * 8;
    srcB[c] = Bw + (size_t)(n0 + row) * 512 + slot * 8;
    dstOff[c] = chunk * 1024;
  }

  int offA[4], offB[4];
  #pragma unroll
  for (int mi = 0; mi < 4; ++mi) {
    int row = wr * 64 + mi * 16 + l15;
    offA[mi] = row * 64 + ((l4 ^ ((row >> 1) & 3)) * 16);
  }
  #pragma unroll
  for (int ni = 0; ni < 4; ++ni) {
    int row = wc * 64 + ni * 16 + l15;
    offB[ni] = row * 64 + ((l4 ^ ((row >> 1) & 3)) * 16);
  }

  f32x4 acc[4][4];
  #pragma unroll
  for (int mi = 0; mi < 4; ++mi)
    #pragma unroll
    for (int ni = 0; ni < 4; ++ni)
      acc[mi][ni] = (f32x4){0.f, 0.f, 0.f, 0.f};

  #pragma unroll
  for (int c = 0; c < 2; ++c) {
    GLOAD_LDS16(srcA[c], ((char*)As[0]) + dstOff[c]);
    GLOAD_LDS16(srcB[c], ((char*)Bs[0]) + dstOff[c]);
  }
  __builtin_amdgcn_sched_barrier(0);

  #pragma unroll
  for (int it = 0; it < 16; ++it) {
    const int cur = it & 1;
    asm volatile("s_waitcnt vmcnt(0)" ::: "memory");
    __builtin_amdgcn_sched_barrier(0);
    __builtin_amdgcn_s_barrier();
    __builtin_amdgcn_sched_barrier(0);
    if (it < 15) {
      const int k1 = (it + 1) * 32;
      #pragma unroll
      for (int c = 0; c < 2; ++c) {
        GLOAD_LDS16(srcA[c] + k1, ((char*)As[cur ^ 1]) + dstOff[c]);
        GLOAD_LDS16(srcB[c] + k1, ((char*)Bs[cur ^ 1]) + dstOff[c]);
      }
    }
    {
      bf16x8 af[4], bfv[4];
      #pragma unroll
      for (int mi = 0; mi < 4; ++mi)
        af[mi] = *(const bf16x8*)(((const char*)As[cur]) + offA[mi]);
      #pragma unroll
      for (int ni = 0; ni < 4; ++ni)
        bfv[ni] = *(const bf16x8*)(((const char*)Bs[cur]) + offB[ni]);
      #pragma unroll
      for (int mi = 0; mi < 4; ++mi)
        #pragma unroll
        for (int ni = 0; ni < 4; ++ni)
          acc[mi][ni] = __builtin_amdgcn_mfma_f32_16x16x32_bf16(af[mi], bfv[ni], acc[mi][ni], 0, 0, 0);
    }
    __builtin_amdgcn_sched_barrier(0);
  }

  #pragma unroll
  for (int mi = 0; mi < 4; ++mi) {
    #pragma unroll
    for (int r = 0; r < 4; ++r) {
      int gm = m0 + wr * 64 + mi * 16 + l4 * 4 + r;
      if (gm < M) {
        #pragma unroll
        for (int ni = 0; ni < 4; ++ni) {
          int gcol = n0 + wc * 64 + ni * 16 + l15;
          float v = acc[mi][ni][r] + bias[gcol];
          if (EPI == 2) v = tanh_fast(v);
          out[(size_t)gm * 512 + gcol] = v;
        }
      }
    }
  }
}

// ---------------- host side ----------------

extern "C" void kernel_launch(void* const* d_in, const int* in_sizes, int n_in,
                              void* d_out, int out_size, void* d_ws, size_t ws_size,
                              hipStream_t stream) {
  const float* h  = (const float*)d_in[0];
  const float* g  = (const float*)d_in[1];
  const int*   vn = (const int*)d_in[2];
  const int*   nid= (const int*)d_in[3];
  const float* Wq = (const float*)d_in[4];
  const float* Wk = (const float*)d_in[5];
  const float* ab = (const float*)d_in[6];
  const float* Ws = (const float*)d_in[7];
  const float* W  = (const float*)d_in[9];
  const float* b  = (const float*)d_in[10];

  const int B = in_sizes[3];          // 100000
  const int C = in_sizes[1] / D_DIM;  // 1000

  char* wsb = (char*)d_ws;
  size_t off = 0;
  auto alloc = [&](size_t bytes) -> void* {
    void* p = wsb + off;
    off += (bytes + 255) & ~(size_t)255;
    return p;
  };

  unsigned short* hbf   = (unsigned short*)alloc((size_t)B * 512 * 2);
  unsigned short* gbf   = (unsigned short*)alloc((size_t)C * 512 * 2);
  unsigned short* ctxbf = (unsigned short*)alloc((size_t)C * 512 * 2);
  unsigned short* Wk_bf = (unsigned short*)alloc((size_t)512 * 512 * 2);  // contiguous
  unsigned short* Wq_bf = (unsigned short*)alloc((size_t)512 * 512 * 2);  // with Wk_bf
  unsigned short* W_bf  = (unsigned short*)alloc((size_t)512 * 512 * 2);  // and Wq_bf
  float* qb    = (float*)alloc((size_t)C * 512 * 4);
  float* ctx   = (float*)alloc((size_t)C * 512 * 4);
  float* score = (float*)alloc((size_t)B * 4);
  float* ev    = (float*)alloc((size_t)B * 4);
  int*   cl    = (int*)alloc((size_t)B * 4);
  int*   order = (int*)alloc((size_t)B * 4);
  int*      counts = (int*)alloc((size_t)C * 4);
  unsigned* smax   = (unsigned*)alloc((size_t)C * 4);
  float*    denom  = (float*)alloc((size_t)C * 4);
  int* starts = (int*)alloc((size_t)(C + 1) * 4);
  int* cursor = (int*)alloc((size_t)C * 4);
  (void)ws_size; (void)n_in; (void)out_size;

  size_t zlen = (size_t)((char*)denom - (char*)counts) + (size_t)C * 4;
  hipMemsetAsync(counts, 0, zlen, stream);
  hipMemsetAsync(score, 0, (size_t)B * 4, stream);

  cvt_f32_bf16_k<<<(B * 512 / 4 + 255) / 256, 256, 0, stream>>>(h, hbf, B * 512 / 4);
  cvt_f32_bf16_k<<<(C * 512 / 4 + 255) / 256, 256, 0, stream>>>(g, gbf, C * 512 / 4);
  const int n4w = 512 * 512 / 4;
  cvt3_f32_bf16_k<<<(3 * n4w + 255) / 256, 256, 0, stream>>>(Wk, Wq, W, Wk_bf, n4w);

  prep_cluster_k<<<(B + 255) / 256, 256, 0, stream>>>(vn, nid, cl, counts, B);
  prefix_k<<<1, 1024, 0, stream>>>(counts, starts, cursor, C);
  scatter_k<<<(B + 255) / 256, 256, 0, stream>>>(cl, cursor, order, B);

  // qb = g @ Wq^T + attn_bias
  gemm128_k<0><<<4 * ((C + 127) / 128), 256, 0, stream>>>(gbf, Wq_bf, C, ab, qb);

  // score[m] += per-256-col-block sum of tanh(h@Wk^T + qb[cl])·Ws
  // (bs dropped: softmax invariant to constant shift)
  gemm256_phase_score_k<<<2 * ((B + 255) / 256), 512, 0, stream>>>(
      hbf, Wk_bf, B, qb, cl, Ws, score);

  seg_max_k<<<(B + 255) / 256, 256, 0, stream>>>(score, cl, smax, B);
  seg_expsum_k<<<(B + 255) / 256, 256, 0, stream>>>(score, cl, smax, ev, denom, B);
  ctx_k<<<C, 256, 0, stream>>>(hbf, ev, order, starts, denom, ctx);

  cvt_f32_bf16_k<<<(C * 512 / 4 + 255) / 256, 256, 0, stream>>>(ctx, ctxbf, C * 512 / 4);

  // out = tanh(ctx @ W^T + b)
  gemm128_k<2><<<4 * ((C + 127) / 128), 256, 0, stream>>>(ctxbf, W_bf, C, b, (float*)d_out);
}

// Round 14
// 247.786 us; speedup vs baseline: 1.1061x; 1.1061x over previous
//
#include <hip/hip_runtime.h>
#include <stdint.h>

#define D_DIM 512

typedef __attribute__((ext_vector_type(8))) short bf16x8;
typedef __attribute__((ext_vector_type(4))) float f32x4;
typedef __attribute__((ext_vector_type(4))) short short4_t;
typedef __attribute__((ext_vector_type(4))) float float4_t;

__device__ __forceinline__ unsigned short f2bf(float f) {
  unsigned u = __float_as_uint(f);
  u += 0x7FFFu + ((u >> 16) & 1u);
  return (unsigned short)(u >> 16);
}

__device__ __forceinline__ float bf2f(unsigned short s) {
  return __uint_as_float(((unsigned)s) << 16);
}

__device__ __forceinline__ float tanh_fast(float x) {
  float e = __expf(2.0f * x);
  return 1.0f - 2.0f / (e + 1.0f);
}

#define GLOAD_LDS16(gsrc, ldst) \
  __builtin_amdgcn_global_load_lds((const __attribute__((address_space(1))) void*)(gsrc), \
                                   (__attribute__((address_space(3))) void*)(ldst), 16, 0, 0)

// ---------------- small utility kernels ----------------

__global__ void cvt_f32_bf16_k(const float* __restrict__ in, unsigned short* __restrict__ out, int n4) {
  int i = blockIdx.x * blockDim.x + threadIdx.x;
  if (i < n4) {
    float4_t v = ((const float4_t*)in)[i];
    short4_t s;
    s.x = (short)f2bf(v.x); s.y = (short)f2bf(v.y);
    s.z = (short)f2bf(v.z); s.w = (short)f2bf(v.w);
    ((short4_t*)out)[i] = s;
  }
}

__global__ void cvt3_f32_bf16_k(const float* __restrict__ a, const float* __restrict__ b,
                                const float* __restrict__ c, unsigned short* __restrict__ out,
                                int n4each) {
  int i = blockIdx.x * blockDim.x + threadIdx.x;
  if (i >= 3 * n4each) return;
  int sel = i / n4each, j = i - sel * n4each;
  const float* src = (sel == 0) ? a : (sel == 1) ? b : c;
  float4_t v = ((const float4_t*)src)[j];
  short4_t s;
  s.x = (short)f2bf(v.x); s.y = (short)f2bf(v.y);
  s.z = (short)f2bf(v.z); s.w = (short)f2bf(v.w);
  ((short4_t*)out)[i] = s;
}

__global__ void prep_cluster_k(const int* __restrict__ vn, const int* __restrict__ nid,
                               int* __restrict__ cl, int* __restrict__ counts, int B) {
  int i = blockIdx.x * blockDim.x + threadIdx.x;
  if (i < B) {
    int c = vn[2 * nid[i] + 1];
    cl[i] = c;
    atomicAdd(&counts[c], 1);
  }
}

__global__ void prefix_k(const int* __restrict__ counts, int* __restrict__ starts,
                         int* __restrict__ cursor, int C) {
  __shared__ int sh[1024];
  int t = threadIdx.x;
  int v = (t < C) ? counts[t] : 0;
  sh[t] = v;
  __syncthreads();
  for (int off = 1; off < 1024; off <<= 1) {
    int x = (t >= off) ? sh[t - off] : 0;
    __syncthreads();
    sh[t] += x;
    __syncthreads();
  }
  if (t < C) { int st = sh[t] - v; starts[t] = st; cursor[t] = st; }
  if (t == 1023) starts[C] = sh[1023];
}

__global__ void scatter_k(const int* __restrict__ cl, int* __restrict__ cursor,
                          int* __restrict__ order, int B) {
  int i = blockIdx.x * blockDim.x + threadIdx.x;
  if (i < B) {
    int pos = atomicAdd(&cursor[cl[i]], 1);
    order[pos] = i;
  }
}

__device__ __forceinline__ unsigned enc_f(float f) {
  unsigned u = __float_as_uint(f);
  return (u & 0x80000000u) ? ~u : (u | 0x80000000u);
}
__device__ __forceinline__ float dec_f(unsigned u) {
  return __uint_as_float((u & 0x80000000u) ? (u & 0x7FFFFFFFu) : ~u);
}

__global__ void seg_max_k(const float* __restrict__ score, const int* __restrict__ cl,
                          unsigned* __restrict__ smax, int B) {
  int i = blockIdx.x * blockDim.x + threadIdx.x;
  if (i < B) atomicMax(&smax[cl[i]], enc_f(score[i]));
}

__global__ void seg_expsum_k(const float* __restrict__ score, const int* __restrict__ cl,
                             const unsigned* __restrict__ smax, float* __restrict__ ev,
                             float* __restrict__ denom, int B) {
  int i = blockIdx.x * blockDim.x + threadIdx.x;
  if (i < B) {
    int c = cl[i];
    float x = __expf(score[i] - dec_f(smax[c]));
    ev[i] = x;
    atomicAdd(&denom[c], x);
  }
}

__global__ __launch_bounds__(256)
void ctx_k(const unsigned short* __restrict__ hbf, const float* __restrict__ ev,
           const int* __restrict__ order, const int* __restrict__ starts,
           const float* __restrict__ denom, float* __restrict__ ctx) {
  int c = blockIdx.x;
  int t = threadIdx.x;
  int s0 = starts[c], s1 = starts[c + 1];
  float a0 = 0.f, a1 = 0.f;
  int j = s0;
  for (; j + 3 < s1; j += 4) {
    int i0 = order[j], i1 = order[j + 1], i2 = order[j + 2], i3 = order[j + 3];
    float e0 = ev[i0], e1 = ev[i1], e2 = ev[i2], e3 = ev[i3];
    unsigned u0 = *(const unsigned*)(hbf + (size_t)i0 * D_DIM + t * 2);
    unsigned u1 = *(const unsigned*)(hbf + (size_t)i1 * D_DIM + t * 2);
    unsigned u2 = *(const unsigned*)(hbf + (size_t)i2 * D_DIM + t * 2);
    unsigned u3 = *(const unsigned*)(hbf + (size_t)i3 * D_DIM + t * 2);
    a0 += e0 * bf2f((unsigned short)u0) + e1 * bf2f((unsigned short)u1)
        + e2 * bf2f((unsigned short)u2) + e3 * bf2f((unsigned short)u3);
    a1 += e0 * bf2f((unsigned short)(u0 >> 16)) + e1 * bf2f((unsigned short)(u1 >> 16))
        + e2 * bf2f((unsigned short)(u2 >> 16)) + e3 * bf2f((unsigned short)(u3 >> 16));
  }
  for (; j < s1; ++j) {
    int i0 = order[j];
    float e0 = ev[i0];
    unsigned u0 = *(const unsigned*)(hbf + (size_t)i0 * D_DIM + t * 2);
    a0 += e0 * bf2f((unsigned short)u0);
    a1 += e0 * bf2f((unsigned short)(u0 >> 16));
  }
  float inv = 1.0f / denom[c];
  float2 r = make_float2(a0 * inv, a1 * inv);
  *(float2*)(&ctx[(size_t)c * D_DIM + t * 2]) = r;
}

// ====== 256x256 score GEMM, BK=64 dbuf, 1024 threads (16 waves of 64x64) ======
// R9/R11 structure (best: 134us) with ONE change: BK 32 -> 64, halving the
// K-step count (16 -> 8). Rationale: the measured per-step wall (6576cy) has a
// fixed ~2-3k cy residue beyond VMEM (3277cy) + LDS (1250cy) -- barrier
// convergence + issue/drain tails. Halving the step count amortizes that
// residue at UNCHANGED traffic (400MB), residency (1 block/CU), and regs
// (acc 64 AGPR + ~64 VGPR = 128 -> exactly 4 waves/SIMD for the 16-wave block).
// LDS: 2 bufs x (A 32KB + B 32KB) = 128KB + 5KB epilogue = 133KB <= 160KB.
// Rows now 128B = 8 slots of 16B; swizzle phys_slot = slot ^ (row&7)
// (R2-R4: measured 0 conflicts). gload_lds writes linearly; SOURCE address
// carries the inverse swizzle (rule #21). One barrier per step (R9 scheme):
// top {vmcnt(0); s_barrier} -> issue tile t+1 into buf^1 (its readers all
// passed this barrier with values in registers) -> ds_read + MFMA (ks=0,1).
__global__ __launch_bounds__(1024)
void gemm256sq_score_k(const unsigned short* __restrict__ Abf,
                       const unsigned short* __restrict__ Bw, int M,
                       const float* __restrict__ qb, const int* __restrict__ cl,
                       const float* __restrict__ Ws, float* __restrict__ out)
{
  // AB[buf]: A = shorts [0, 16384) (256 rows x 64), B = [16384, 32768)
  __shared__ unsigned short AB[2][32768];
  __shared__ float red[256][4];
  __shared__ int clds[256];

  const int t = threadIdx.x;
  const int lane = t & 63;
  const int w = t >> 6;                 // 0..15
  const int wr = w >> 2, wc = w & 3;    // wave tile: rows wr*64, cols wc*64
  const int l15 = lane & 15, l4 = lane >> 4;

  // m204 bijective XCD-chunk swizzle
  int id;
  {
    int nwg = gridDim.x;
    int q = nwg >> 3, r = nwg & 7;
    int xcd = blockIdx.x & 7, pos = blockIdx.x >> 3;
    id = (xcd < r ? xcd * (q + 1) : r * (q + 1) + (xcd - r) * q) + pos;
  }
  const int n0 = (id & 1) * 256;        // N fastest: 2 siblings share A panel
  const int m0 = (id >> 1) * 256;

  // ---- staging: wave w stages A rows w*16..w*16+15 and B rows likewise.
  // chunk c in {0,1}: row = w*16 + c*8 + (lane>>3); slot = lane&7;
  // source slot = (lane&7) ^ (row&7) = (lane&7) ^ (lane>>3).
  const int rin = lane >> 3;
  const int sslot = (lane & 7) ^ rin;
  const unsigned short* srcA[2];
  const unsigned short* srcB[2];
  #pragma unroll
  for (int c = 0; c < 2; ++c) {
    int row = w * 16 + c * 8 + rin;
    int rowA = m0 + row; if (rowA > M - 1) rowA = M - 1;
    srcA[c] = Abf + (size_t)rowA * 512 + sslot * 8;
    srcB[c] = Bw + (size_t)(n0 + row) * 512 + sslot * 8;
  }
  // LDS dst byte offsets (within one buf): A chunk -> w*2048 + c*1024;
  // B same + 32768.
  // fragment byte offsets within one buf, per ks (K-half)
  int offA[4][2], offB[4][2];
  #pragma unroll
  for (int mi = 0; mi < 4; ++mi) {
    int row = wr * 64 + mi * 16 + l15;
    #pragma unroll
    for (int ks = 0; ks < 2; ++ks)
      offA[mi][ks] = row * 128 + (((ks * 4 + l4) ^ (row & 7)) * 16);
  }
  #pragma unroll
  for (int ni = 0; ni < 4; ++ni) {
    int row = wc * 64 + ni * 16 + l15;
    #pragma unroll
    for (int ks = 0; ks < 2; ++ks)
      offB[ni][ks] = 32768 + row * 128 + (((ks * 4 + l4) ^ (row & 7)) * 16);
  }

  f32x4 acc[4][4];
  #pragma unroll
  for (int mi = 0; mi < 4; ++mi)
    #pragma unroll
    for (int ni = 0; ni < 4; ++ni)
      acc[mi][ni] = (f32x4){0.f, 0.f, 0.f, 0.f};

  // prologue: issue tile 0 into buffer 0 (4 gloads per wave)
  #pragma unroll
  for (int c = 0; c < 2; ++c) {
    GLOAD_LDS16(srcA[c], ((char*)&AB[0][0]) + w * 2048 + c * 1024);
    GLOAD_LDS16(srcB[c], ((char*)&AB[0][0]) + 32768 + w * 2048 + c * 1024);
  }
  __builtin_amdgcn_sched_barrier(0);

  #pragma unroll
  for (int kt = 0; kt < 8; ++kt) {
    const int b = kt & 1;
    // top: drain this tile's staging, sync all waves
    asm volatile("s_waitcnt vmcnt(0)" ::: "memory");
    __builtin_amdgcn_sched_barrier(0);
    __builtin_amdgcn_s_barrier();
    __builtin_amdgcn_sched_barrier(0);

    // issue tile kt+1 into buf b^1 (its step-(kt-1) readers passed the barrier
    // with their fragment values already in registers)
    if (kt < 7) {
      const int k1 = (kt + 1) * 64;     // +128B per step along the row
      #pragma unroll
      for (int c = 0; c < 2; ++c) {
        GLOAD_LDS16(srcA[c] + k1, ((char*)&AB[b ^ 1][0]) + w * 2048 + c * 1024);
        GLOAD_LDS16(srcB[c] + k1, ((char*)&AB[b ^ 1][0]) + 32768 + w * 2048 + c * 1024);
      }
    }

    #pragma unroll
    for (int ks = 0; ks < 2; ++ks) {
      bf16x8 a[4], bv[4];
      #pragma unroll
      for (int mi = 0; mi < 4; ++mi)
        a[mi] = *(const bf16x8*)(((const char*)&AB[b][0]) + offA[mi][ks]);
      #pragma unroll
      for (int ni = 0; ni < 4; ++ni)
        bv[ni] = *(const bf16x8*)(((const char*)&AB[b][0]) + offB[ni][ks]);
      __builtin_amdgcn_s_setprio(1);
      #pragma unroll
      for (int mi = 0; mi < 4; ++mi)
        #pragma unroll
        for (int ni = 0; ni < 4; ++ni)
          acc[mi][ni] = __builtin_amdgcn_mfma_f32_16x16x32_bf16(a[mi], bv[ni], acc[mi][ni], 0, 0, 0);
      __builtin_amdgcn_s_setprio(0);
    }
    __builtin_amdgcn_sched_barrier(0);
  }

  // ---- epilogue: fused additive-attention partial score over 256 cols ----
  if (t < 256) {
    int gm = m0 + t;
    clds[t] = cl[gm < M ? gm : M - 1];
  }
  __syncthreads();
  #pragma unroll
  for (int mi = 0; mi < 4; ++mi) {
    #pragma unroll
    for (int r = 0; r < 4; ++r) {
      int rowt = wr * 64 + mi * 16 + l4 * 4 + r;
      int c = clds[rowt];
      const float* qrow = &qb[(size_t)c * 512];
      float s = 0.f;
      #pragma unroll
      for (int ni = 0; ni < 4; ++ni) {
        int gcol = n0 + wc * 64 + ni * 16 + l15;
        float x = acc[mi][ni][r] + qrow[gcol];
        s += tanh_fast(x) * Ws[gcol];
      }
      s += __shfl_xor(s, 1);
      s += __shfl_xor(s, 2);
      s += __shfl_xor(s, 4);
      s += __shfl_xor(s, 8);
      if (l15 == 0) red[rowt][wc] = s;
    }
  }
  __syncthreads();
  if (t < 256) {
    int gm = m0 + t;
    if (gm < M) atomicAdd(&out[gm], red[t][0] + red[t][1] + red[t][2] + red[t][3]);
  }
}

// --- bf16 MFMA GEMM: 128x128 tile, BK=32 -- small GEMMs only ---
template<int EPI>
__global__ __launch_bounds__(256)
void gemm128_k(const unsigned short* __restrict__ Abf,
               const unsigned short* __restrict__ Bw, int M,
               const float* __restrict__ bias, float* __restrict__ out)
{
  __shared__ unsigned short As[2][128 * 32];
  __shared__ unsigned short Bs[2][128 * 32];

  const int t = threadIdx.x;
  const int lane = t & 63;
  const int w = t >> 6;
  const int wr = w >> 1, wc = w & 1;
  const int l15 = lane & 15, l4 = lane >> 4;

  const int nwg = gridDim.x;
  int id = blockIdx.x;
  if ((nwg & 7) == 0) id = (id & 7) * (nwg >> 3) + (id >> 3);
  const int n0 = (id & 3) * 128;
  const int m0 = (id >> 2) * 128;

  const int rin = lane >> 2;
  const int sl = lane & 3;

  const unsigned short* srcA[2];
  const unsigned short* srcB[2];
  int dstOff[2];
  #pragma unroll
  for (int c = 0; c < 2; ++c) {
    int chunk = w * 2 + c;
    int row = chunk * 16 + rin;
    int slot = sl ^ ((row >> 1) & 3);
    int ga = m0 + row; if (ga > M - 1) ga = M - 1;
    srcA[c] = Abf + (size_t)ga * 512 + slot * 8;
    srcB[c] = Bw + (size_t)(n0 + row) * 512 + slot * 8;
    dstOff[c] = chunk * 1024;
  }

  int offA[4], offB[4];
  #pragma unroll
  for (int mi = 0; mi < 4; ++mi) {
    int row = wr * 64 + mi * 16 + l15;
    offA[mi] = row * 64 + ((l4 ^ ((row >> 1) & 3)) * 16);
  }
  #pragma unroll
  for (int ni = 0; ni < 4; ++ni) {
    int row = wc * 64 + ni * 16 + l15;
    offB[ni] = row * 64 + ((l4 ^ ((row >> 1) & 3)) * 16);
  }

  f32x4 acc[4][4];
  #pragma unroll
  for (int mi = 0; mi < 4; ++mi)
    #pragma unroll
    for (int ni = 0; ni < 4; ++ni)
      acc[mi][ni] = (f32x4){0.f, 0.f, 0.f, 0.f};

  #pragma unroll
  for (int c = 0; c < 2; ++c) {
    GLOAD_LDS16(srcA[c], ((char*)As[0]) + dstOff[c]);
    GLOAD_LDS16(srcB[c], ((char*)Bs[0]) + dstOff[c]);
  }
  __builtin_amdgcn_sched_barrier(0);

  #pragma unroll
  for (int it = 0; it < 16; ++it) {
    const int cur = it & 1;
    asm volatile("s_waitcnt vmcnt(0)" ::: "memory");
    __builtin_amdgcn_sched_barrier(0);
    __builtin_amdgcn_s_barrier();
    __builtin_amdgcn_sched_barrier(0);
    if (it < 15) {
      const int k1 = (it + 1) * 32;
      #pragma unroll
      for (int c = 0; c < 2; ++c) {
        GLOAD_LDS16(srcA[c] + k1, ((char*)As[cur ^ 1]) + dstOff[c]);
        GLOAD_LDS16(srcB[c] + k1, ((char*)Bs[cur ^ 1]) + dstOff[c]);
      }
    }
    {
      bf16x8 af[4], bfv[4];
      #pragma unroll
      for (int mi = 0; mi < 4; ++mi)
        af[mi] = *(const bf16x8*)(((const char*)As[cur]) + offA[mi]);
      #pragma unroll
      for (int ni = 0; ni < 4; ++ni)
        bfv[ni] = *(const bf16x8*)(((const char*)Bs[cur]) + offB[ni]);
      #pragma unroll
      for (int mi = 0; mi < 4; ++mi)
        #pragma unroll
        for (int ni = 0; ni < 4; ++ni)
          acc[mi][ni] = __builtin_amdgcn_mfma_f32_16x16x32_bf16(af[mi], bfv[ni], acc[mi][ni], 0, 0, 0);
    }
    __builtin_amdgcn_sched_barrier(0);
  }

  #pragma unroll
  for (int mi = 0; mi < 4; ++mi) {
    #pragma unroll
    for (int r = 0; r < 4; ++r) {
      int gm = m0 + wr * 64 + mi * 16 + l4 * 4 + r;
      if (gm < M) {
        #pragma unroll
        for (int ni = 0; ni < 4; ++ni) {
          int gcol = n0 + wc * 64 + ni * 16 + l15;
          float v = acc[mi][ni][r] + bias[gcol];
          if (EPI == 2) v = tanh_fast(v);
          out[(size_t)gm * 512 + gcol] = v;
        }
      }
    }
  }
}

// ---------------- host side ----------------

extern "C" void kernel_launch(void* const* d_in, const int* in_sizes, int n_in,
                              void* d_out, int out_size, void* d_ws, size_t ws_size,
                              hipStream_t stream) {
  const float* h  = (const float*)d_in[0];
  const float* g  = (const float*)d_in[1];
  const int*   vn = (const int*)d_in[2];
  const int*   nid= (const int*)d_in[3];
  const float* Wq = (const float*)d_in[4];
  const float* Wk = (const float*)d_in[5];
  const float* ab = (const float*)d_in[6];
  const float* Ws = (const float*)d_in[7];
  const float* W  = (const float*)d_in[9];
  const float* b  = (const float*)d_in[10];

  const int B = in_sizes[3];          // 100000
  const int C = in_sizes[1] / D_DIM;  // 1000

  char* wsb = (char*)d_ws;
  size_t off = 0;
  auto alloc = [&](size_t bytes) -> void* {
    void* p = wsb + off;
    off += (bytes + 255) & ~(size_t)255;
    return p;
  };

  unsigned short* hbf   = (unsigned short*)alloc((size_t)B * 512 * 2);
  unsigned short* gbf   = (unsigned short*)alloc((size_t)C * 512 * 2);
  unsigned short* ctxbf = (unsigned short*)alloc((size_t)C * 512 * 2);
  unsigned short* Wk_bf = (unsigned short*)alloc((size_t)512 * 512 * 2);  // contiguous
  unsigned short* Wq_bf = (unsigned short*)alloc((size_t)512 * 512 * 2);  // with Wk_bf
  unsigned short* W_bf  = (unsigned short*)alloc((size_t)512 * 512 * 2);  // and Wq_bf
  float* qb    = (float*)alloc((size_t)C * 512 * 4);
  float* ctx   = (float*)alloc((size_t)C * 512 * 4);
  float* score = (float*)alloc((size_t)B * 4);
  float* ev    = (float*)alloc((size_t)B * 4);
  int*   cl    = (int*)alloc((size_t)B * 4);
  int*   order = (int*)alloc((size_t)B * 4);
  int*      counts = (int*)alloc((size_t)C * 4);
  unsigned* smax   = (unsigned*)alloc((size_t)C * 4);
  float*    denom  = (float*)alloc((size_t)C * 4);
  int* starts = (int*)alloc((size_t)(C + 1) * 4);
  int* cursor = (int*)alloc((size_t)C * 4);
  (void)ws_size; (void)n_in; (void)out_size;

  size_t zlen = (size_t)((char*)denom - (char*)counts) + (size_t)C * 4;
  hipMemsetAsync(counts, 0, zlen, stream);
  hipMemsetAsync(score, 0, (size_t)B * 4, stream);

  cvt_f32_bf16_k<<<(B * 512 / 4 + 255) / 256, 256, 0, stream>>>(h, hbf, B * 512 / 4);
  cvt_f32_bf16_k<<<(C * 512 / 4 + 255) / 256, 256, 0, stream>>>(g, gbf, C * 512 / 4);
  const int n4w = 512 * 512 / 4;
  cvt3_f32_bf16_k<<<(3 * n4w + 255) / 256, 256, 0, stream>>>(Wk, Wq, W, Wk_bf, n4w);

  prep_cluster_k<<<(B + 255) / 256, 256, 0, stream>>>(vn, nid, cl, counts, B);
  prefix_k<<<1, 1024, 0, stream>>>(counts, starts, cursor, C);
  scatter_k<<<(B + 255) / 256, 256, 0, stream>>>(cl, cursor, order, B);

  // qb = g @ Wq^T + attn_bias
  gemm128_k<0><<<4 * ((C + 127) / 128), 256, 0, stream>>>(gbf, Wq_bf, C, ab, qb);

  // score[m] += per-256-col-block sum of tanh(h@Wk^T + qb[cl])·Ws
  // (bs dropped: softmax invariant to constant shift)
  gemm256sq_score_k<<<2 * ((B + 255) / 256), 1024, 0, stream>>>(
      hbf, Wk_bf, B, qb, cl, Ws, score);

  seg_max_k<<<(B + 255) / 256, 256, 0, stream>>>(score, cl, smax, B);
  seg_expsum_k<<<(B + 255) / 256, 256, 0, stream>>>(score, cl, smax, ev, denom, B);
  ctx_k<<<C, 256, 0, stream>>>(hbf, ev, order, starts, denom, ctx);

  cvt_f32_bf16_k<<<(C * 512 / 4 + 255) / 256, 256, 0, stream>>>(ctx, ctxbf, C * 512 / 4);

  // out = tanh(ctx @ W^T + b)
  gemm128_k<2><<<4 * ((C + 127) / 128), 256, 0, stream>>>(ctxbf, W_bf, C, b, (float*)d_out);
}

// Round 15
// 245.670 us; speedup vs baseline: 1.1156x; 1.0086x over previous
//
#include <hip/hip_runtime.h>
#include <stdint.h>

#define D_DIM 512

typedef __attribute__((ext_vector_type(8))) short bf16x8;
typedef __attribute__((ext_vector_type(4))) float f32x4;
typedef __attribute__((ext_vector_type(4))) short short4_t;
typedef __attribute__((ext_vector_type(4))) float float4_t;

__device__ __forceinline__ unsigned short f2bf(float f) {
  unsigned u = __float_as_uint(f);
  u += 0x7FFFu + ((u >> 16) & 1u);
  return (unsigned short)(u >> 16);
}

__device__ __forceinline__ float bf2f(unsigned short s) {
  return __uint_as_float(((unsigned)s) << 16);
}

__device__ __forceinline__ float tanh_fast(float x) {
  float e = __expf(2.0f * x);
  return 1.0f - 2.0f / (e + 1.0f);
}

#define GLOAD_LDS16(gsrc, ldst) \
  __builtin_amdgcn_global_load_lds((const __attribute__((address_space(1))) void*)(gsrc), \
                                   (__attribute__((address_space(3))) void*)(ldst), 16, 0, 0)

// ---------------- small utility kernels ----------------

__global__ void cvt_f32_bf16_k(const float* __restrict__ in, unsigned short* __restrict__ out, int n4) {
  int i = blockIdx.x * blockDim.x + threadIdx.x;
  if (i < n4) {
    float4_t v = ((const float4_t*)in)[i];
    short4_t s;
    s.x = (short)f2bf(v.x); s.y = (short)f2bf(v.y);
    s.z = (short)f2bf(v.z); s.w = (short)f2bf(v.w);
    ((short4_t*)out)[i] = s;
  }
}

__global__ void cvt3_f32_bf16_k(const float* __restrict__ a, const float* __restrict__ b,
                                const float* __restrict__ c, unsigned short* __restrict__ out,
                                int n4each) {
  int i = blockIdx.x * blockDim.x + threadIdx.x;
  if (i >= 3 * n4each) return;
  int sel = i / n4each, j = i - sel * n4each;
  const float* src = (sel == 0) ? a : (sel == 1) ? b : c;
  float4_t v = ((const float4_t*)src)[j];
  short4_t s;
  s.x = (short)f2bf(v.x); s.y = (short)f2bf(v.y);
  s.z = (short)f2bf(v.z); s.w = (short)f2bf(v.w);
  ((short4_t*)out)[i] = s;
}

__global__ void prep_cluster_k(const int* __restrict__ vn, const int* __restrict__ nid,
                               int* __restrict__ cl, int* __restrict__ counts, int B) {
  int i = blockIdx.x * blockDim.x + threadIdx.x;
  if (i < B) {
    int c = vn[2 * nid[i] + 1];
    cl[i] = c;
    atomicAdd(&counts[c], 1);
  }
}

__global__ void prefix_k(const int* __restrict__ counts, int* __restrict__ starts,
                         int* __restrict__ cursor, int C) {
  __shared__ int sh[1024];
  int t = threadIdx.x;
  int v = (t < C) ? counts[t] : 0;
  sh[t] = v;
  __syncthreads();
  for (int off = 1; off < 1024; off <<= 1) {
    int x = (t >= off) ? sh[t - off] : 0;
    __syncthreads();
    sh[t] += x;
    __syncthreads();
  }
  if (t < C) { int st = sh[t] - v; starts[t] = st; cursor[t] = st; }
  if (t == 1023) starts[C] = sh[1023];
}

__global__ void scatter_k(const int* __restrict__ cl, int* __restrict__ cursor,
                          int* __restrict__ order, int B) {
  int i = blockIdx.x * blockDim.x + threadIdx.x;
  if (i < B) {
    int pos = atomicAdd(&cursor[cl[i]], 1);
    order[pos] = i;
  }
}

__device__ __forceinline__ unsigned enc_f(float f) {
  unsigned u = __float_as_uint(f);
  return (u & 0x80000000u) ? ~u : (u | 0x80000000u);
}
__device__ __forceinline__ float dec_f(unsigned u) {
  return __uint_as_float((u & 0x80000000u) ? (u & 0x7FFFFFFFu) : ~u);
}

__global__ void seg_max_k(const float* __restrict__ score, const int* __restrict__ cl,
                          unsigned* __restrict__ smax, int B) {
  int i = blockIdx.x * blockDim.x + threadIdx.x;
  if (i < B) atomicMax(&smax[cl[i]], enc_f(score[i]));
}

__global__ void seg_expsum_k(const float* __restrict__ score, const int* __restrict__ cl,
                             const unsigned* __restrict__ smax, float* __restrict__ ev,
                             float* __restrict__ denom, int B) {
  int i = blockIdx.x * blockDim.x + threadIdx.x;
  if (i < B) {
    int c = cl[i];
    float x = __expf(score[i] - dec_f(smax[c]));
    ev[i] = x;
    atomicAdd(&denom[c], x);
  }
}

__global__ __launch_bounds__(256)
void ctx_k(const unsigned short* __restrict__ hbf, const float* __restrict__ ev,
           const int* __restrict__ order, const int* __restrict__ starts,
           const float* __restrict__ denom, float* __restrict__ ctx) {
  int c = blockIdx.x;
  int t = threadIdx.x;
  int s0 = starts[c], s1 = starts[c + 1];
  float a0 = 0.f, a1 = 0.f;
  int j = s0;
  for (; j + 3 < s1; j += 4) {
    int i0 = order[j], i1 = order[j + 1], i2 = order[j + 2], i3 = order[j + 3];
    float e0 = ev[i0], e1 = ev[i1], e2 = ev[i2], e3 = ev[i3];
    unsigned u0 = *(const unsigned*)(hbf + (size_t)i0 * D_DIM + t * 2);
    unsigned u1 = *(const unsigned*)(hbf + (size_t)i1 * D_DIM + t * 2);
    unsigned u2 = *(const unsigned*)(hbf + (size_t)i2 * D_DIM + t * 2);
    unsigned u3 = *(const unsigned*)(hbf + (size_t)i3 * D_DIM + t * 2);
    a0 += e0 * bf2f((unsigned short)u0) + e1 * bf2f((unsigned short)u1)
        + e2 * bf2f((unsigned short)u2) + e3 * bf2f((unsigned short)u3);
    a1 += e0 * bf2f((unsigned short)(u0 >> 16)) + e1 * bf2f((unsigned short)(u1 >> 16))
        + e2 * bf2f((unsigned short)(u2 >> 16)) + e3 * bf2f((unsigned short)(u3 >> 16));
  }
  for (; j < s1; ++j) {
    int i0 = order[j];
    float e0 = ev[i0];
    unsigned u0 = *(const unsigned*)(hbf + (size_t)i0 * D_DIM + t * 2);
    a0 += e0 * bf2f((unsigned short)u0);
    a1 += e0 * bf2f((unsigned short)(u0 >> 16));
  }
  float inv = 1.0f / denom[c];
  float2 r = make_float2(a0 * inv, a1 * inv);
  *(float2*)(&ctx[(size_t)c * D_DIM + t * 2]) = r;
}

// ====== 256x256 score GEMM, BK=64 dbuf, 1024 threads (16 waves of 64x64) ======
// R14 re-run WITHOUT the register spill: R14's offA[4][2]/offB[4][2] (+8 VGPR)
// crossed the 128-reg boundary of the 16-wave block -> scratch traffic
// (WRITE_SIZE 781KB -> 54MB). Fix: ks=1 fragment offsets are DERIVED, not
// stored -- for swizzle slot^(row&7) with l4<4:
//   off[ks=1] = row*128 + (((4+l4)^(row&7))*16) = off[ks=0] ^ 64
// (bit 2 of l4 is clear so 4+l4 = 4|l4; XOR-by-4 in the slot index = XOR-by-64
// in the byte offset; row bits >= bit 7 are disjoint). Registers return to the
// R9 level. Everything else = R9/R11 proven scheme: one vmcnt(0)+s_barrier per
// step, prefetch kt+1 after the barrier, swizzled source + linear gload_lds
// dest (rule #21), m204 XCD swizzle, 400MB total staged traffic.
__global__ __launch_bounds__(1024)
void gemm256sq_score_k(const unsigned short* __restrict__ Abf,
                       const unsigned short* __restrict__ Bw, int M,
                       const float* __restrict__ qb, const int* __restrict__ cl,
                       const float* __restrict__ Ws, float* __restrict__ out)
{
  // AB[buf]: A = shorts [0, 16384) (256 rows x 64), B = [16384, 32768)
  __shared__ unsigned short AB[2][32768];
  __shared__ float red[256][4];
  __shared__ int clds[256];

  const int t = threadIdx.x;
  const int lane = t & 63;
  const int w = t >> 6;                 // 0..15
  const int wr = w >> 2, wc = w & 3;    // wave tile: rows wr*64, cols wc*64
  const int l15 = lane & 15, l4 = lane >> 4;

  // m204 bijective XCD-chunk swizzle
  int id;
  {
    int nwg = gridDim.x;
    int q = nwg >> 3, r = nwg & 7;
    int xcd = blockIdx.x & 7, pos = blockIdx.x >> 3;
    id = (xcd < r ? xcd * (q + 1) : r * (q + 1) + (xcd - r) * q) + pos;
  }
  const int n0 = (id & 1) * 256;        // N fastest: 2 siblings share A panel
  const int m0 = (id >> 1) * 256;

  // ---- staging: wave w stages A rows w*16..w*16+15 and B rows likewise.
  // chunk c in {0,1}: row = w*16 + c*8 + (lane>>3); slot = lane&7;
  // source slot = (lane&7) ^ (row&7) = (lane&7) ^ (lane>>3).
  const int rin = lane >> 3;
  const int sslot = (lane & 7) ^ rin;
  const unsigned short* srcA[2];
  const unsigned short* srcB[2];
  #pragma unroll
  for (int c = 0; c < 2; ++c) {
    int row = w * 16 + c * 8 + rin;
    int rowA = m0 + row; if (rowA > M - 1) rowA = M - 1;
    srcA[c] = Abf + (size_t)rowA * 512 + sslot * 8;
    srcB[c] = Bw + (size_t)(n0 + row) * 512 + sslot * 8;
  }

  // fragment byte offsets for ks=0; ks=1 = off ^ 64 (see header comment)
  int offA[4], offB[4];
  #pragma unroll
  for (int mi = 0; mi < 4; ++mi) {
    int row = wr * 64 + mi * 16 + l15;
    offA[mi] = row * 128 + ((l4 ^ (row & 7)) * 16);
  }
  #pragma unroll
  for (int ni = 0; ni < 4; ++ni) {
    int row = wc * 64 + ni * 16 + l15;
    offB[ni] = 32768 + row * 128 + ((l4 ^ (row & 7)) * 16);
  }

  f32x4 acc[4][4];
  #pragma unroll
  for (int mi = 0; mi < 4; ++mi)
    #pragma unroll
    for (int ni = 0; ni < 4; ++ni)
      acc[mi][ni] = (f32x4){0.f, 0.f, 0.f, 0.f};

  // prologue: issue tile 0 into buffer 0 (4 gloads per wave)
  #pragma unroll
  for (int c = 0; c < 2; ++c) {
    GLOAD_LDS16(srcA[c], ((char*)&AB[0][0]) + w * 2048 + c * 1024);
    GLOAD_LDS16(srcB[c], ((char*)&AB[0][0]) + 32768 + w * 2048 + c * 1024);
  }
  __builtin_amdgcn_sched_barrier(0);

  #pragma unroll
  for (int kt = 0; kt < 8; ++kt) {
    const int b = kt & 1;
    // top: drain this tile's staging, sync all waves
    asm volatile("s_waitcnt vmcnt(0)" ::: "memory");
    __builtin_amdgcn_sched_barrier(0);
    __builtin_amdgcn_s_barrier();
    __builtin_amdgcn_sched_barrier(0);

    // issue tile kt+1 into buf b^1 (its step-(kt-1) readers passed the barrier
    // with their fragment values already in registers)
    if (kt < 7) {
      const int k1 = (kt + 1) * 64;     // +128B per step along the row
      #pragma unroll
      for (int c = 0; c < 2; ++c) {
        GLOAD_LDS16(srcA[c] + k1, ((char*)&AB[b ^ 1][0]) + w * 2048 + c * 1024);
        GLOAD_LDS16(srcB[c] + k1, ((char*)&AB[b ^ 1][0]) + 32768 + w * 2048 + c * 1024);
      }
    }

    #pragma unroll
    for (int ks = 0; ks < 2; ++ks) {
      const int kx = ks ? 64 : 0;       // compile-time XOR per ks
      bf16x8 a[4], bv[4];
      #pragma unroll
      for (int mi = 0; mi < 4; ++mi)
        a[mi] = *(const bf16x8*)(((const char*)&AB[b][0]) + (offA[mi] ^ kx));
      #pragma unroll
      for (int ni = 0; ni < 4; ++ni)
        bv[ni] = *(const bf16x8*)(((const char*)&AB[b][0]) + (offB[ni] ^ kx));
      __builtin_amdgcn_s_setprio(1);
      #pragma unroll
      for (int mi = 0; mi < 4; ++mi)
        #pragma unroll
        for (int ni = 0; ni < 4; ++ni)
          acc[mi][ni] = __builtin_amdgcn_mfma_f32_16x16x32_bf16(a[mi], bv[ni], acc[mi][ni], 0, 0, 0);
      __builtin_amdgcn_s_setprio(0);
    }
    __builtin_amdgcn_sched_barrier(0);
  }

  // ---- epilogue: fused additive-attention partial score over 256 cols ----
  if (t < 256) {
    int gm = m0 + t;
    clds[t] = cl[gm < M ? gm : M - 1];
  }
  __syncthreads();
  #pragma unroll
  for (int mi = 0; mi < 4; ++mi) {
    #pragma unroll
    for (int r = 0; r < 4; ++r) {
      int rowt = wr * 64 + mi * 16 + l4 * 4 + r;
      int c = clds[rowt];
      const float* qrow = &qb[(size_t)c * 512];
      float s = 0.f;
      #pragma unroll
      for (int ni = 0; ni < 4; ++ni) {
        int gcol = n0 + wc * 64 + ni * 16 + l15;
        float x = acc[mi][ni][r] + qrow[gcol];
        s += tanh_fast(x) * Ws[gcol];
      }
      s += __shfl_xor(s, 1);
      s += __shfl_xor(s, 2);
      s += __shfl_xor(s, 4);
      s += __shfl_xor(s, 8);
      if (l15 == 0) red[rowt][wc] = s;
    }
  }
  __syncthreads();
  if (t < 256) {
    int gm = m0 + t;
    if (gm < M) atomicAdd(&out[gm], red[t][0] + red[t][1] + red[t][2] + red[t][3]);
  }
}

// --- bf16 MFMA GEMM: 128x128 tile, BK=32 -- small GEMMs only ---
template<int EPI>
__global__ __launch_bounds__(256)
void gemm128_k(const unsigned short* __restrict__ Abf,
               const unsigned short* __restrict__ Bw, int M,
               const float* __restrict__ bias, float* __restrict__ out)
{
  __shared__ unsigned short As[2][128 * 32];
  __shared__ unsigned short Bs[2][128 * 32];

  const int t = threadIdx.x;
  const int lane = t & 63;
  const int w = t >> 6;
  const int wr = w >> 1, wc = w & 1;
  const int l15 = lane & 15, l4 = lane >> 4;

  const int nwg = gridDim.x;
  int id = blockIdx.x;
  if ((nwg & 7) == 0) id = (id & 7) * (nwg >> 3) + (id >> 3);
  const int n0 = (id & 3) * 128;
  const int m0 = (id >> 2) * 128;

  const int rin = lane >> 2;
  const int sl = lane & 3;

  const unsigned short* srcA[2];
  const unsigned short* srcB[2];
  int dstOff[2];
  #pragma unroll
  for (int c = 0; c < 2; ++c) {
    int chunk = w * 2 + c;
    int row = chunk * 16 + rin;
    int slot = sl ^ ((row >> 1) & 3);
    int ga = m0 + row; if (ga > M - 1) ga = M - 1;
    srcA[c] = Abf + (size_t)ga * 512 + slot * 8;
    srcB[c] = Bw + (size_t)(n0 + row) * 512 + slot * 8;
    dstOff[c] = chunk * 1024;
  }

  int offA[4], offB[4];
  #pragma unroll
  for (int mi = 0; mi < 4; ++mi) {
    int row = wr * 64 + mi * 16 + l15;
    offA[mi] = row * 64 + ((l4 ^ ((row >> 1) & 3)) * 16);
  }
  #pragma unroll
  for (int ni = 0; ni < 4; ++ni) {
    int row = wc * 64 + ni * 16 + l15;
    offB[ni] = row * 64 + ((l4 ^ ((row >> 1) & 3)) * 16);
  }

  f32x4 acc[4][4];
  #pragma unroll
  for (int mi = 0; mi < 4; ++mi)
    #pragma unroll
    for (int ni = 0; ni < 4; ++ni)
      acc[mi][ni] = (f32x4){0.f, 0.f, 0.f, 0.f};

  #pragma unroll
  for (int c = 0; c < 2; ++c) {
    GLOAD_LDS16(srcA[c], ((char*)As[0]) + dstOff[c]);
    GLOAD_LDS16(srcB[c], ((char*)Bs[0]) + dstOff[c]);
  }
  __builtin_amdgcn_sched_barrier(0);

  #pragma unroll
  for (int it = 0; it < 16; ++it) {
    const int cur = it & 1;
    asm volatile("s_waitcnt vmcnt(0)" ::: "memory");
    __builtin_amdgcn_sched_barrier(0);
    __builtin_amdgcn_s_barrier();
    __builtin_amdgcn_sched_barrier(0);
    if (it < 15) {
      const int k1 = (it + 1) * 32;
      #pragma unroll
      for (int c = 0; c < 2; ++c) {
        GLOAD_LDS16(srcA[c] + k1, ((char*)As[cur ^ 1]) + dstOff[c]);
        GLOAD_LDS16(srcB[c] + k1, ((char*)Bs[cur ^ 1]) + dstOff[c]);
      }
    }
    {
      bf16x8 af[4], bfv[4];
      #pragma unroll
      for (int mi = 0; mi < 4; ++mi)
        af[mi] = *(const bf16x8*)(((const char*)As[cur]) + offA[mi]);
      #pragma unroll
      for (int ni = 0; ni < 4; ++ni)
        bfv[ni] = *(const bf16x8*)(((const char*)Bs[cur]) + offB[ni]);
      #pragma unroll
      for (int mi = 0; mi < 4; ++mi)
        #pragma unroll
        for (int ni = 0; ni < 4; ++ni)
          acc[mi][ni] = __builtin_amdgcn_mfma_f32_16x16x32_bf16(af[mi], bfv[ni], acc[mi][ni], 0, 0, 0);
    }
    __builtin_amdgcn_sched_barrier(0);
  }

  #pragma unroll
  for (int mi = 0; mi < 4; ++mi) {
    #pragma unroll
    for (int r = 0; r < 4; ++r) {
      int gm = m0 + wr * 64 + mi * 16 + l4 * 4 + r;
      if (gm < M) {
        #pragma unroll
        for (int ni = 0; ni < 4; ++ni) {
          int gcol = n0 + wc * 64 + ni * 16 + l15;
          float v = acc[mi][ni][r] + bias[gcol];
          if (EPI == 2) v = tanh_fast(v);
          out[(size_t)gm * 512 + gcol] = v;
        }
      }
    }
  }
}

// ---------------- host side ----------------

extern "C" void kernel_launch(void* const* d_in, const int* in_sizes, int n_in,
                              void* d_out, int out_size, void* d_ws, size_t ws_size,
                              hipStream_t stream) {
  const float* h  = (const float*)d_in[0];
  const float* g  = (const float*)d_in[1];
  const int*   vn = (const int*)d_in[2];
  const int*   nid= (const int*)d_in[3];
  const float* Wq = (const float*)d_in[4];
  const float* Wk = (const float*)d_in[5];
  const float* ab = (const float*)d_in[6];
  const float* Ws = (const float*)d_in[7];
  const float* W  = (const float*)d_in[9];
  const float* b  = (const float*)d_in[10];

  const int B = in_sizes[3];          // 100000
  const int C = in_sizes[1] / D_DIM;  // 1000

  char* wsb = (char*)d_ws;
  size_t off = 0;
  auto alloc = [&](size_t bytes) -> void* {
    void* p = wsb + off;
    off += (bytes + 255) & ~(size_t)255;
    return p;
  };

  unsigned short* hbf   = (unsigned short*)alloc((size_t)B * 512 * 2);
  unsigned short* gbf   = (unsigned short*)alloc((size_t)C * 512 * 2);
  unsigned short* ctxbf = (unsigned short*)alloc((size_t)C * 512 * 2);
  unsigned short* Wk_bf = (unsigned short*)alloc((size_t)512 * 512 * 2);  // contiguous
  unsigned short* Wq_bf = (unsigned short*)alloc((size_t)512 * 512 * 2);  // with Wk_bf
  unsigned short* W_bf  = (unsigned short*)alloc((size_t)512 * 512 * 2);  // and Wq_bf
  float* qb    = (float*)alloc((size_t)C * 512 * 4);
  float* ctx   = (float*)alloc((size_t)C * 512 * 4);
  float* score = (float*)alloc((size_t)B * 4);
  float* ev    = (float*)alloc((size_t)B * 4);
  int*   cl    = (int*)alloc((size_t)B * 4);
  int*   order = (int*)alloc((size_t)B * 4);
  int*      counts = (int*)alloc((size_t)C * 4);
  unsigned* smax   = (unsigned*)alloc((size_t)C * 4);
  float*    denom  = (float*)alloc((size_t)C * 4);
  int* starts = (int*)alloc((size_t)(C + 1) * 4);
  int* cursor = (int*)alloc((size_t)C * 4);
  (void)ws_size; (void)n_in; (void)out_size;

  size_t zlen = (size_t)((char*)denom - (char*)counts) + (size_t)C * 4;
  hipMemsetAsync(counts, 0, zlen, stream);
  hipMemsetAsync(score, 0, (size_t)B * 4, stream);

  cvt_f32_bf16_k<<<(B * 512 / 4 + 255) / 256, 256, 0, stream>>>(h, hbf, B * 512 / 4);
  cvt_f32_bf16_k<<<(C * 512 / 4 + 255) / 256, 256, 0, stream>>>(g, gbf, C * 512 / 4);
  const int n4w = 512 * 512 / 4;
  cvt3_f32_bf16_k<<<(3 * n4w + 255) / 256, 256, 0, stream>>>(Wk, Wq, W, Wk_bf, n4w);

  prep_cluster_k<<<(B + 255) / 256, 256, 0, stream>>>(vn, nid, cl, counts, B);
  prefix_k<<<1, 1024, 0, stream>>>(counts, starts, cursor, C);
  scatter_k<<<(B + 255) / 256, 256, 0, stream>>>(cl, cursor, order, B);

  // qb = g @ Wq^T + attn_bias
  gemm128_k<0><<<4 * ((C + 127) / 128), 256, 0, stream>>>(gbf, Wq_bf, C, ab, qb);

  // score[m] += per-256-col-block sum of tanh(h@Wk^T + qb[cl])·Ws
  // (bs dropped: softmax invariant to constant shift)
  gemm256sq_score_k<<<2 * ((B + 255) / 256), 1024, 0, stream>>>(
      hbf, Wk_bf, B, qb, cl, Ws, score);

  seg_max_k<<<(B + 255) / 256, 256, 0, stream>>>(score, cl, smax, B);
  seg_expsum_k<<<(B + 255) / 256, 256, 0, stream>>>(score, cl, smax, ev, denom, B);
  ctx_k<<<C, 256, 0, stream>>>(hbf, ev, order, starts, denom, ctx);

  cvt_f32_bf16_k<<<(C * 512 / 4 + 255) / 256, 256, 0, stream>>>(ctx, ctxbf, C * 512 / 4);

  // out = tanh(ctx @ W^T + b)
  gemm128_k<2><<<4 * ((C + 127) / 128), 256, 0, stream>>>(ctxbf, W_bf, C, b, (float*)d_out);
}

// Round 16
// 237.148 us; speedup vs baseline: 1.1557x; 1.0359x over previous
//
#include <hip/hip_runtime.h>
#include <stdint.h>

#define D_DIM 512

typedef __attribute__((ext_vector_type(8))) short bf16x8;
typedef __attribute__((ext_vector_type(4))) float f32x4;
typedef __attribute__((ext_vector_type(4))) short short4_t;
typedef __attribute__((ext_vector_type(4))) float float4_t;

__device__ __forceinline__ unsigned short f2bf(float f) {
  unsigned u = __float_as_uint(f);
  u += 0x7FFFu + ((u >> 16) & 1u);
  return (unsigned short)(u >> 16);
}

__device__ __forceinline__ float bf2f(unsigned short s) {
  return __uint_as_float(((unsigned)s) << 16);
}

__device__ __forceinline__ float tanh_fast(float x) {
  float e = __expf(2.0f * x);
  return 1.0f - 2.0f / (e + 1.0f);
}

#define GLOAD_LDS16(gsrc, ldst) \
  __builtin_amdgcn_global_load_lds((const __attribute__((address_space(1))) void*)(gsrc), \
                                   (__attribute__((address_space(3))) void*)(ldst), 16, 0, 0)

// ---------------- small utility kernels ----------------

__global__ void cvt_f32_bf16_k(const float* __restrict__ in, unsigned short* __restrict__ out, int n4) {
  int i = blockIdx.x * blockDim.x + threadIdx.x;
  if (i < n4) {
    float4_t v = ((const float4_t*)in)[i];
    short4_t s;
    s.x = (short)f2bf(v.x); s.y = (short)f2bf(v.y);
    s.z = (short)f2bf(v.z); s.w = (short)f2bf(v.w);
    ((short4_t*)out)[i] = s;
  }
}

__global__ void cvt3_f32_bf16_k(const float* __restrict__ a, const float* __restrict__ b,
                                const float* __restrict__ c, unsigned short* __restrict__ out,
                                int n4each) {
  int i = blockIdx.x * blockDim.x + threadIdx.x;
  if (i >= 3 * n4each) return;
  int sel = i / n4each, j = i - sel * n4each;
  const float* src = (sel == 0) ? a : (sel == 1) ? b : c;
  float4_t v = ((const float4_t*)src)[j];
  short4_t s;
  s.x = (short)f2bf(v.x); s.y = (short)f2bf(v.y);
  s.z = (short)f2bf(v.z); s.w = (short)f2bf(v.w);
  ((short4_t*)out)[i] = s;
}

__global__ void prep_cluster_k(const int* __restrict__ vn, const int* __restrict__ nid,
                               int* __restrict__ cl, int* __restrict__ counts, int B) {
  int i = blockIdx.x * blockDim.x + threadIdx.x;
  if (i < B) {
    int c = vn[2 * nid[i] + 1];
    cl[i] = c;
    atomicAdd(&counts[c], 1);
  }
}

__global__ void prefix_k(const int* __restrict__ counts, int* __restrict__ starts,
                         int* __restrict__ cursor, int C) {
  __shared__ int sh[1024];
  int t = threadIdx.x;
  int v = (t < C) ? counts[t] : 0;
  sh[t] = v;
  __syncthreads();
  for (int off = 1; off < 1024; off <<= 1) {
    int x = (t >= off) ? sh[t - off] : 0;
    __syncthreads();
    sh[t] += x;
    __syncthreads();
  }
  if (t < C) { int st = sh[t] - v; starts[t] = st; cursor[t] = st; }
  if (t == 1023) starts[C] = sh[1023];
}

__global__ void scatter_k(const int* __restrict__ cl, int* __restrict__ cursor,
                          int* __restrict__ order, int B) {
  int i = blockIdx.x * blockDim.x + threadIdx.x;
  if (i < B) {
    int pos = atomicAdd(&cursor[cl[i]], 1);
    order[pos] = i;
  }
}

__device__ __forceinline__ unsigned enc_f(float f) {
  unsigned u = __float_as_uint(f);
  return (u & 0x80000000u) ? ~u : (u | 0x80000000u);
}
__device__ __forceinline__ float dec_f(unsigned u) {
  return __uint_as_float((u & 0x80000000u) ? (u & 0x7FFFFFFFu) : ~u);
}

__global__ void seg_max_k(const float* __restrict__ score, const int* __restrict__ cl,
                          unsigned* __restrict__ smax, int B) {
  int i = blockIdx.x * blockDim.x + threadIdx.x;
  if (i < B) atomicMax(&smax[cl[i]], enc_f(score[i]));
}

__global__ void seg_expsum_k(const float* __restrict__ score, const int* __restrict__ cl,
                             const unsigned* __restrict__ smax, float* __restrict__ ev,
                             float* __restrict__ denom, int B) {
  int i = blockIdx.x * blockDim.x + threadIdx.x;
  if (i < B) {
    int c = cl[i];
    float x = __expf(score[i] - dec_f(smax[c]));
    ev[i] = x;
    atomicAdd(&denom[c], x);
  }
}

__global__ __launch_bounds__(256)
void ctx_k(const unsigned short* __restrict__ hbf, const float* __restrict__ ev,
           const int* __restrict__ order, const int* __restrict__ starts,
           const float* __restrict__ denom, float* __restrict__ ctx) {
  int c = blockIdx.x;
  int t = threadIdx.x;
  int s0 = starts[c], s1 = starts[c + 1];
  float a0 = 0.f, a1 = 0.f;
  int j = s0;
  for (; j + 3 < s1; j += 4) {
    int i0 = order[j], i1 = order[j + 1], i2 = order[j + 2], i3 = order[j + 3];
    float e0 = ev[i0], e1 = ev[i1], e2 = ev[i2], e3 = ev[i3];
    unsigned u0 = *(const unsigned*)(hbf + (size_t)i0 * D_DIM + t * 2);
    unsigned u1 = *(const unsigned*)(hbf + (size_t)i1 * D_DIM + t * 2);
    unsigned u2 = *(const unsigned*)(hbf + (size_t)i2 * D_DIM + t * 2);
    unsigned u3 = *(const unsigned*)(hbf + (size_t)i3 * D_DIM + t * 2);
    a0 += e0 * bf2f((unsigned short)u0) + e1 * bf2f((unsigned short)u1)
        + e2 * bf2f((unsigned short)u2) + e3 * bf2f((unsigned short)u3);
    a1 += e0 * bf2f((unsigned short)(u0 >> 16)) + e1 * bf2f((unsigned short)(u1 >> 16))
        + e2 * bf2f((unsigned short)(u2 >> 16)) + e3 * bf2f((unsigned short)(u3 >> 16));
  }
  for (; j < s1; ++j) {
    int i0 = order[j];
    float e0 = ev[i0];
    unsigned u0 = *(const unsigned*)(hbf + (size_t)i0 * D_DIM + t * 2);
    a0 += e0 * bf2f((unsigned short)u0);
    a1 += e0 * bf2f((unsigned short)(u0 >> 16));
  }
  float inv = 1.0f / denom[c];
  float2 r = make_float2(a0 * inv, a1 * inv);
  *(float2*)(&ctx[(size_t)c * D_DIM + t * 2]) = r;
}

// ====== 256x256 score GEMM, BK=32, TRIPLE-buffered depth-2 prefetch ======
// Session-best configuration (R11: 133.9us, 0 bank conflicts, 0 spill).
// 16 waves of 64x64 (acc 64 AGPR + ~64 VGPR = 128 -> exactly 4 waves/SIMD);
// 3 LDS buffers, depth-2 prefetch with counted vmcnt(2) (tile kt+1 stays in
// flight across the top-of-body wait); one barrier per K-step; swizzle
// slot^((row>>1)&3) on 64B rows (0 conflicts measured); gload_lds linear dest
// + pre-swizzled source (rule #21); m204 bijective XCD swizzle, N-fastest.
// Total staged traffic 400MB -- the register-optimal minimum for this family.
__global__ __launch_bounds__(1024)
void gemm256sq_score_k(const unsigned short* __restrict__ Abf,
                       const unsigned short* __restrict__ Bw, int M,
                       const float* __restrict__ qb, const int* __restrict__ cl,
                       const float* __restrict__ Ws, float* __restrict__ out)
{
  // AB[buf]: A = elements [0, 8192) (256 rows x 32), B = [8192, 16384)
  __shared__ unsigned short AB[3][16384];
  __shared__ float red[256][4];
  __shared__ int clds[256];

  const int t = threadIdx.x;
  const int lane = t & 63;
  const int w = t >> 6;                 // 0..15
  const int wr = w >> 2, wc = w & 3;    // wave tile: rows wr*64, cols wc*64
  const int l15 = lane & 15, l4 = lane >> 4;

  // m204 bijective XCD-chunk swizzle
  int id;
  {
    int nwg = gridDim.x;
    int q = nwg >> 3, r = nwg & 7;
    int xcd = blockIdx.x & 7, pos = blockIdx.x >> 3;
    id = (xcd < r ? xcd * (q + 1) : r * (q + 1) + (xcd - r) * q) + pos;
  }
  const int n0 = (id & 1) * 256;        // N fastest: 2 siblings share A panel
  const int m0 = (id >> 1) * 256;

  // ---- staging: wave w stages A-chunk w and B-chunk w (1KB = 16 rows x 64B) ----
  const int rin = lane >> 2;
  const int lrow = w * 16 + rin;                    // row within tile 0..255
  const int sslot = (lane & 3) ^ ((lrow >> 1) & 3);
  int rowA = m0 + lrow; if (rowA > M - 1) rowA = M - 1;
  const unsigned short* srcA = Abf + (size_t)rowA * 512 + sslot * 8;
  const unsigned short* srcB = Bw + (size_t)(n0 + lrow) * 512 + sslot * 8;

  // fragment LDS byte offsets within one 32KB buffer
  int offA[4], offB[4];
  #pragma unroll
  for (int mi = 0; mi < 4; ++mi) {
    int row = wr * 64 + mi * 16 + l15;
    offA[mi] = row * 64 + ((l4 ^ ((row >> 1) & 3)) * 16);
  }
  #pragma unroll
  for (int ni = 0; ni < 4; ++ni) {
    int row = wc * 64 + ni * 16 + l15;
    offB[ni] = 16384 + row * 64 + ((l4 ^ ((row >> 1) & 3)) * 16);
  }

  f32x4 acc[4][4];
  #pragma unroll
  for (int mi = 0; mi < 4; ++mi)
    #pragma unroll
    for (int ni = 0; ni < 4; ++ni)
      acc[mi][ni] = (f32x4){0.f, 0.f, 0.f, 0.f};

  // prologue: issue tiles 0 and 1 into buffers 0 and 1 (tile-grouped order)
  GLOAD_LDS16(srcA, ((char*)&AB[0][0]) + w * 1024);
  GLOAD_LDS16(srcB, ((char*)&AB[0][8192]) + w * 1024);
  GLOAD_LDS16(srcA + 32, ((char*)&AB[1][0]) + w * 1024);
  GLOAD_LDS16(srcB + 32, ((char*)&AB[1][8192]) + w * 1024);
  __builtin_amdgcn_sched_barrier(0);

  #pragma unroll
  for (int kt = 0; kt < 16; ++kt) {
    const int b = kt % 3;
    // counted drain: tile kt's loads (issued 2 bodies ago) land; kt+1 stays in flight
    if (kt < 15) {
      asm volatile("s_waitcnt vmcnt(2)" ::: "memory");
    } else {
      asm volatile("s_waitcnt vmcnt(0)" ::: "memory");
    }
    __builtin_amdgcn_sched_barrier(0);
    __builtin_amdgcn_s_barrier();
    __builtin_amdgcn_sched_barrier(0);

    // issue tile kt+2 into buf (kt+2)%3 (compile-time constant after unroll)
    if (kt < 14) {
      const int k2 = (kt + 2) * 32;     // +64B per step
      GLOAD_LDS16(srcA + k2, ((char*)&AB[(kt + 2) % 3][0]) + w * 1024);
      GLOAD_LDS16(srcB + k2, ((char*)&AB[(kt + 2) % 3][8192]) + w * 1024);
    }

    bf16x8 a[4], bv[4];
    #pragma unroll
    for (int mi = 0; mi < 4; ++mi)
      a[mi] = *(const bf16x8*)(((const char*)AB[b]) + offA[mi]);
    #pragma unroll
    for (int ni = 0; ni < 4; ++ni)
      bv[ni] = *(const bf16x8*)(((const char*)AB[b]) + offB[ni]);
    __builtin_amdgcn_s_setprio(1);
    #pragma unroll
    for (int mi = 0; mi < 4; ++mi)
      #pragma unroll
      for (int ni = 0; ni < 4; ++ni)
        acc[mi][ni] = __builtin_amdgcn_mfma_f32_16x16x32_bf16(a[mi], bv[ni], acc[mi][ni], 0, 0, 0);
    __builtin_amdgcn_s_setprio(0);
    __builtin_amdgcn_sched_barrier(0);
  }

  // ---- epilogue: fused additive-attention partial score over 256 cols ----
  if (t < 256) {
    int gm = m0 + t;
    clds[t] = cl[gm < M ? gm : M - 1];
  }
  __syncthreads();
  #pragma unroll
  for (int mi = 0; mi < 4; ++mi) {
    #pragma unroll
    for (int r = 0; r < 4; ++r) {
      int rowt = wr * 64 + mi * 16 + l4 * 4 + r;
      int c = clds[rowt];
      const float* qrow = &qb[(size_t)c * 512];
      float s = 0.f;
      #pragma unroll
      for (int ni = 0; ni < 4; ++ni) {
        int gcol = n0 + wc * 64 + ni * 16 + l15;
        float x = acc[mi][ni][r] + qrow[gcol];
        s += tanh_fast(x) * Ws[gcol];
      }
      s += __shfl_xor(s, 1);
      s += __shfl_xor(s, 2);
      s += __shfl_xor(s, 4);
      s += __shfl_xor(s, 8);
      if (l15 == 0) red[rowt][wc] = s;
    }
  }
  __syncthreads();
  if (t < 256) {
    int gm = m0 + t;
    if (gm < M) atomicAdd(&out[gm], red[t][0] + red[t][1] + red[t][2] + red[t][3]);
  }
}

// --- bf16 MFMA GEMM: 128x128 tile, BK=32 -- small GEMMs only ---
template<int EPI>
__global__ __launch_bounds__(256)
void gemm128_k(const unsigned short* __restrict__ Abf,
               const unsigned short* __restrict__ Bw, int M,
               const float* __restrict__ bias, float* __restrict__ out)
{
  __shared__ unsigned short As[2][128 * 32];
  __shared__ unsigned short Bs[2][128 * 32];

  const int t = threadIdx.x;
  const int lane = t & 63;
  const int w = t >> 6;
  const int wr = w >> 1, wc = w & 1;
  const int l15 = lane & 15, l4 = lane >> 4;

  const int nwg = gridDim.x;
  int id = blockIdx.x;
  if ((nwg & 7) == 0) id = (id & 7) * (nwg >> 3) + (id >> 3);
  const int n0 = (id & 3) * 128;
  const int m0 = (id >> 2) * 128;

  const int rin = lane >> 2;
  const int sl = lane & 3;

  const unsigned short* srcA[2];
  const unsigned short* srcB[2];
  int dstOff[2];
  #pragma unroll
  for (int c = 0; c < 2; ++c) {
    int chunk = w * 2 + c;
    int row = chunk * 16 + rin;
    int slot = sl ^ ((row >> 1) & 3);
    int ga = m0 + row; if (ga > M - 1) ga = M - 1;
    srcA[c] = Abf + (size_t)ga * 512 + slot * 8;
    srcB[c] = Bw + (size_t)(n0 + row) * 512 + slot * 8;
    dstOff[c] = chunk * 1024;
  }

  int offA[4], offB[4];
  #pragma unroll
  for (int mi = 0; mi < 4; ++mi) {
    int row = wr * 64 + mi * 16 + l15;
    offA[mi] = row * 64 + ((l4 ^ ((row >> 1) & 3)) * 16);
  }
  #pragma unroll
  for (int ni = 0; ni < 4; ++ni) {
    int row = wc * 64 + ni * 16 + l15;
    offB[ni] = row * 64 + ((l4 ^ ((row >> 1) & 3)) * 16);
  }

  f32x4 acc[4][4];
  #pragma unroll
  for (int mi = 0; mi < 4; ++mi)
    #pragma unroll
    for (int ni = 0; ni < 4; ++ni)
      acc[mi][ni] = (f32x4){0.f, 0.f, 0.f, 0.f};

  #pragma unroll
  for (int c = 0; c < 2; ++c) {
    GLOAD_LDS16(srcA[c], ((char*)As[0]) + dstOff[c]);
    GLOAD_LDS16(srcB[c], ((char*)Bs[0]) + dstOff[c]);
  }
  __builtin_amdgcn_sched_barrier(0);

  #pragma unroll
  for (int it = 0; it < 16; ++it) {
    const int cur = it & 1;
    asm volatile("s_waitcnt vmcnt(0)" ::: "memory");
    __builtin_amdgcn_sched_barrier(0);
    __builtin_amdgcn_s_barrier();
    __builtin_amdgcn_sched_barrier(0);
    if (it < 15) {
      const int k1 = (it + 1) * 32;
      #pragma unroll
      for (int c = 0; c < 2; ++c) {
        GLOAD_LDS16(srcA[c] + k1, ((char*)As[cur ^ 1]) + dstOff[c]);
        GLOAD_LDS16(srcB[c] + k1, ((char*)Bs[cur ^ 1]) + dstOff[c]);
      }
    }
    {
      bf16x8 af[4], bfv[4];
      #pragma unroll
      for (int mi = 0; mi < 4; ++mi)
        af[mi] = *(const bf16x8*)(((const char*)As[cur]) + offA[mi]);
      #pragma unroll
      for (int ni = 0; ni < 4; ++ni)
        bfv[ni] = *(const bf16x8*)(((const char*)Bs[cur]) + offB[ni]);
      #pragma unroll
      for (int mi = 0; mi < 4; ++mi)
        #pragma unroll
        for (int ni = 0; ni < 4; ++ni)
          acc[mi][ni] = __builtin_amdgcn_mfma_f32_16x16x32_bf16(af[mi], bfv[ni], acc[mi][ni], 0, 0, 0);
    }
    __builtin_amdgcn_sched_barrier(0);
  }

  #pragma unroll
  for (int mi = 0; mi < 4; ++mi) {
    #pragma unroll
    for (int r = 0; r < 4; ++r) {
      int gm = m0 + wr * 64 + mi * 16 + l4 * 4 + r;
      if (gm < M) {
        #pragma unroll
        for (int ni = 0; ni < 4; ++ni) {
          int gcol = n0 + wc * 64 + ni * 16 + l15;
          float v = acc[mi][ni][r] + bias[gcol];
          if (EPI == 2) v = tanh_fast(v);
          out[(size_t)gm * 512 + gcol] = v;
        }
      }
    }
  }
}

// ---------------- host side ----------------

extern "C" void kernel_launch(void* const* d_in, const int* in_sizes, int n_in,
                              void* d_out, int out_size, void* d_ws, size_t ws_size,
                              hipStream_t stream) {
  const float* h  = (const float*)d_in[0];
  const float* g  = (const float*)d_in[1];
  const int*   vn = (const int*)d_in[2];
  const int*   nid= (const int*)d_in[3];
  const float* Wq = (const float*)d_in[4];
  const float* Wk = (const float*)d_in[5];
  const float* ab = (const float*)d_in[6];
  const float* Ws = (const float*)d_in[7];
  const float* W  = (const float*)d_in[9];
  const float* b  = (const float*)d_in[10];

  const int B = in_sizes[3];          // 100000
  const int C = in_sizes[1] / D_DIM;  // 1000

  char* wsb = (char*)d_ws;
  size_t off = 0;
  auto alloc = [&](size_t bytes) -> void* {
    void* p = wsb + off;
    off += (bytes + 255) & ~(size_t)255;
    return p;
  };

  unsigned short* hbf   = (unsigned short*)alloc((size_t)B * 512 * 2);
  unsigned short* gbf   = (unsigned short*)alloc((size_t)C * 512 * 2);
  unsigned short* ctxbf = (unsigned short*)alloc((size_t)C * 512 * 2);
  unsigned short* Wk_bf = (unsigned short*)alloc((size_t)512 * 512 * 2);  // contiguous
  unsigned short* Wq_bf = (unsigned short*)alloc((size_t)512 * 512 * 2);  // with Wk_bf
  unsigned short* W_bf  = (unsigned short*)alloc((size_t)512 * 512 * 2);  // and Wq_bf
  float* qb    = (float*)alloc((size_t)C * 512 * 4);
  float* ctx   = (float*)alloc((size_t)C * 512 * 4);
  float* score = (float*)alloc((size_t)B * 4);
  float* ev    = (float*)alloc((size_t)B * 4);
  int*   cl    = (int*)alloc((size_t)B * 4);
  int*   order = (int*)alloc((size_t)B * 4);
  int*      counts = (int*)alloc((size_t)C * 4);
  unsigned* smax   = (unsigned*)alloc((size_t)C * 4);
  float*    denom  = (float*)alloc((size_t)C * 4);
  int* starts = (int*)alloc((size_t)(C + 1) * 4);
  int* cursor = (int*)alloc((size_t)C * 4);
  (void)ws_size; (void)n_in; (void)out_size;

  size_t zlen = (size_t)((char*)denom - (char*)counts) + (size_t)C * 4;
  hipMemsetAsync(counts, 0, zlen, stream);
  hipMemsetAsync(score, 0, (size_t)B * 4, stream);

  cvt_f32_bf16_k<<<(B * 512 / 4 + 255) / 256, 256, 0, stream>>>(h, hbf, B * 512 / 4);
  cvt_f32_bf16_k<<<(C * 512 / 4 + 255) / 256, 256, 0, stream>>>(g, gbf, C * 512 / 4);
  const int n4w = 512 * 512 / 4;
  cvt3_f32_bf16_k<<<(3 * n4w + 255) / 256, 256, 0, stream>>>(Wk, Wq, W, Wk_bf, n4w);

  prep_cluster_k<<<(B + 255) / 256, 256, 0, stream>>>(vn, nid, cl, counts, B);
  prefix_k<<<1, 1024, 0, stream>>>(counts, starts, cursor, C);
  scatter_k<<<(B + 255) / 256, 256, 0, stream>>>(cl, cursor, order, B);

  // qb = g @ Wq^T + attn_bias
  gemm128_k<0><<<4 * ((C + 127) / 128), 256, 0, stream>>>(gbf, Wq_bf, C, ab, qb);

  // score[m] += per-256-col-block sum of tanh(h@Wk^T + qb[cl])·Ws
  // (bs dropped: softmax invariant to constant shift)
  gemm256sq_score_k<<<2 * ((B + 255) / 256), 1024, 0, stream>>>(
      hbf, Wk_bf, B, qb, cl, Ws, score);

  seg_max_k<<<(B + 255) / 256, 256, 0, stream>>>(score, cl, smax, B);
  seg_expsum_k<<<(B + 255) / 256, 256, 0, stream>>>(score, cl, smax, ev, denom, B);
  ctx_k<<<C, 256, 0, stream>>>(hbf, ev, order, starts, denom, ctx);

  cvt_f32_bf16_k<<<(C * 512 / 4 + 255) / 256, 256, 0, stream>>>(ctx, ctxbf, C * 512 / 4);

  // out = tanh(ctx @ W^T + b)
  gemm128_k<2><<<4 * ((C + 127) / 128), 256, 0, stream>>>(ctxbf, W_bf, C, b, (float*)d_out);
}

// Round 17
// 227.814 us; speedup vs baseline: 1.2031x; 1.0410x over previous
//
#include <hip/hip_runtime.h>
#include <stdint.h>

#define D_DIM 512

typedef __attribute__((ext_vector_type(8))) short bf16x8;
typedef __attribute__((ext_vector_type(4))) float f32x4;
typedef __attribute__((ext_vector_type(4))) short short4_t;
typedef __attribute__((ext_vector_type(4))) float float4_t;

__device__ __forceinline__ unsigned short f2bf(float f) {
  unsigned u = __float_as_uint(f);
  u += 0x7FFFu + ((u >> 16) & 1u);
  return (unsigned short)(u >> 16);
}

__device__ __forceinline__ float bf2f(unsigned short s) {
  return __uint_as_float(((unsigned)s) << 16);
}

__device__ __forceinline__ float tanh_fast(float x) {
  float e = __expf(2.0f * x);
  return 1.0f - 2.0f / (e + 1.0f);
}

#define GLOAD_LDS16(gsrc, ldst) \
  __builtin_amdgcn_global_load_lds((const __attribute__((address_space(1))) void*)(gsrc), \
                                   (__attribute__((address_space(3))) void*)(ldst), 16, 0, 0)

// ---------------- small utility kernels ----------------

__device__ __forceinline__ void cvt4_at(const float* __restrict__ in,
                                        unsigned short* __restrict__ out, int i) {
  float4_t v = ((const float4_t*)in)[i];
  short4_t s;
  s.x = (short)f2bf(v.x); s.y = (short)f2bf(v.y);
  s.z = (short)f2bf(v.z); s.w = (short)f2bf(v.w);
  ((short4_t*)out)[i] = s;
}

__global__ void cvt_f32_bf16_k(const float* __restrict__ in, unsigned short* __restrict__ out, int n4) {
  int i = blockIdx.x * blockDim.x + threadIdx.x;
  if (i < n4) cvt4_at(in, out, i);
}

// FUSED prologue: h->bf16 (dominant, BW-bound) + g->bf16 + 3 weights->bf16 +
// prep_cluster, grid-partitioned. Saves 3 launches + serialization gaps; the
// small segments (~3MB traffic + B-gather) ride inside the h-convert's shadow.
__global__ void prologue_k(const float* __restrict__ h, const float* __restrict__ g,
                           const float* __restrict__ Wk, const float* __restrict__ Wq,
                           const float* __restrict__ W,
                           const int* __restrict__ vn, const int* __restrict__ nid,
                           unsigned short* __restrict__ hbf, unsigned short* __restrict__ gbf,
                           unsigned short* __restrict__ Wbf3,  // Wk|Wq|W contiguous
                           int* __restrict__ cl, int* __restrict__ counts,
                           int B, int C) {
  const int n4h = B * 128;              // B*512/4
  const int n4g = C * 128;
  const int nbH = (n4h + 255) >> 8;
  const int nbG = (n4g + 255) >> 8;
  const int nbW = (3 * 65536 + 255) >> 8;   // 768
  int b = blockIdx.x;
  int t = threadIdx.x;
  if (b < nbH) {
    int i = b * 256 + t;
    if (i < n4h) cvt4_at(h, hbf, i);
  } else if (b < nbH + nbG) {
    int i = (b - nbH) * 256 + t;
    if (i < n4g) cvt4_at(g, gbf, i);
  } else if (b < nbH + nbG + nbW) {
    int i = (b - nbH - nbG) * 256 + t;  // < 196608
    int sel = i >> 16, j = i & 65535;   // 65536 f32x4 per weight matrix
    const float* src = (sel == 0) ? Wk : (sel == 1) ? Wq : W;
    float4_t v = ((const float4_t*)src)[j];
    short4_t s;
    s.x = (short)f2bf(v.x); s.y = (short)f2bf(v.y);
    s.z = (short)f2bf(v.z); s.w = (short)f2bf(v.w);
    ((short4_t*)Wbf3)[i] = s;
  } else {
    int i = (b - nbH - nbG - nbW) * 256 + t;
    if (i < B) {
      int c = vn[2 * nid[i] + 1];
      cl[i] = c;
      atomicAdd(&counts[c], 1);
    }
  }
}

__global__ void prefix_k(const int* __restrict__ counts, int* __restrict__ starts,
                         int* __restrict__ cursor, int C) {
  __shared__ int sh[1024];
  int t = threadIdx.x;
  int v = (t < C) ? counts[t] : 0;
  sh[t] = v;
  __syncthreads();
  for (int off = 1; off < 1024; off <<= 1) {
    int x = (t >= off) ? sh[t - off] : 0;
    __syncthreads();
    sh[t] += x;
    __syncthreads();
  }
  if (t < C) { int st = sh[t] - v; starts[t] = st; cursor[t] = st; }
  if (t == 1023) starts[C] = sh[1023];
}

__global__ void scatter_k(const int* __restrict__ cl, int* __restrict__ cursor,
                          int* __restrict__ order, int B) {
  int i = blockIdx.x * blockDim.x + threadIdx.x;
  if (i < B) {
    int pos = atomicAdd(&cursor[cl[i]], 1);
    order[pos] = i;
  }
}

__device__ __forceinline__ unsigned enc_f(float f) {
  unsigned u = __float_as_uint(f);
  return (u & 0x80000000u) ? ~u : (u | 0x80000000u);
}
__device__ __forceinline__ float dec_f(unsigned u) {
  return __uint_as_float((u & 0x80000000u) ? (u & 0x7FFFFFFFu) : ~u);
}

__global__ void seg_max_k(const float* __restrict__ score, const int* __restrict__ cl,
                          unsigned* __restrict__ smax, int B) {
  int i = blockIdx.x * blockDim.x + threadIdx.x;
  if (i < B) atomicMax(&smax[cl[i]], enc_f(score[i]));
}

__global__ void seg_expsum_k(const float* __restrict__ score, const int* __restrict__ cl,
                             const unsigned* __restrict__ smax, float* __restrict__ ev,
                             float* __restrict__ denom, int B) {
  int i = blockIdx.x * blockDim.x + threadIdx.x;
  if (i < B) {
    int c = cl[i];
    float x = __expf(score[i] - dec_f(smax[c]));
    ev[i] = x;
    atomicAdd(&denom[c], x);
  }
}

__global__ __launch_bounds__(256)
void ctx_k(const unsigned short* __restrict__ hbf, const float* __restrict__ ev,
           const int* __restrict__ order, const int* __restrict__ starts,
           const float* __restrict__ denom, float* __restrict__ ctx) {
  int c = blockIdx.x;
  int t = threadIdx.x;
  int s0 = starts[c], s1 = starts[c + 1];
  float a0 = 0.f, a1 = 0.f;
  int j = s0;
  for (; j + 3 < s1; j += 4) {
    int i0 = order[j], i1 = order[j + 1], i2 = order[j + 2], i3 = order[j + 3];
    float e0 = ev[i0], e1 = ev[i1], e2 = ev[i2], e3 = ev[i3];
    unsigned u0 = *(const unsigned*)(hbf + (size_t)i0 * D_DIM + t * 2);
    unsigned u1 = *(const unsigned*)(hbf + (size_t)i1 * D_DIM + t * 2);
    unsigned u2 = *(const unsigned*)(hbf + (size_t)i2 * D_DIM + t * 2);
    unsigned u3 = *(const unsigned*)(hbf + (size_t)i3 * D_DIM + t * 2);
    a0 += e0 * bf2f((unsigned short)u0) + e1 * bf2f((unsigned short)u1)
        + e2 * bf2f((unsigned short)u2) + e3 * bf2f((unsigned short)u3);
    a1 += e0 * bf2f((unsigned short)(u0 >> 16)) + e1 * bf2f((unsigned short)(u1 >> 16))
        + e2 * bf2f((unsigned short)(u2 >> 16)) + e3 * bf2f((unsigned short)(u3 >> 16));
  }
  for (; j < s1; ++j) {
    int i0 = order[j];
    float e0 = ev[i0];
    unsigned u0 = *(const unsigned*)(hbf + (size_t)i0 * D_DIM + t * 2);
    a0 += e0 * bf2f((unsigned short)u0);
    a1 += e0 * bf2f((unsigned short)(u0 >> 16));
  }
  float inv = 1.0f / denom[c];
  float2 r = make_float2(a0 * inv, a1 * inv);
  *(float2*)(&ctx[(size_t)c * D_DIM + t * 2]) = r;
}

// ====== 256x256 score GEMM, BK=32, TRIPLE-buffered depth-2 prefetch ======
// Session-best configuration (R11/R16: ~129us, 0 bank conflicts, 0 spill).
// 16 waves of 64x64 (acc 64 AGPR + ~64 VGPR = 128 -> exactly 4 waves/SIMD);
// 3 LDS buffers, depth-2 prefetch with counted vmcnt(2); one barrier per step;
// swizzle slot^((row>>1)&3) on 64B rows (0 conflicts); gload_lds linear dest +
// pre-swizzled source (rule #21); m204 bijective XCD swizzle, N-fastest.
__global__ __launch_bounds__(1024)
void gemm256sq_score_k(const unsigned short* __restrict__ Abf,
                       const unsigned short* __restrict__ Bw, int M,
                       const float* __restrict__ qb, const int* __restrict__ cl,
                       const float* __restrict__ Ws, float* __restrict__ out)
{
  __shared__ unsigned short AB[3][16384];
  __shared__ float red[256][4];
  __shared__ int clds[256];

  const int t = threadIdx.x;
  const int lane = t & 63;
  const int w = t >> 6;
  const int wr = w >> 2, wc = w & 3;
  const int l15 = lane & 15, l4 = lane >> 4;

  int id;
  {
    int nwg = gridDim.x;
    int q = nwg >> 3, r = nwg & 7;
    int xcd = blockIdx.x & 7, pos = blockIdx.x >> 3;
    id = (xcd < r ? xcd * (q + 1) : r * (q + 1) + (xcd - r) * q) + pos;
  }
  const int n0 = (id & 1) * 256;
  const int m0 = (id >> 1) * 256;

  const int rin = lane >> 2;
  const int lrow = w * 16 + rin;
  const int sslot = (lane & 3) ^ ((lrow >> 1) & 3);
  int rowA = m0 + lrow; if (rowA > M - 1) rowA = M - 1;
  const unsigned short* srcA = Abf + (size_t)rowA * 512 + sslot * 8;
  const unsigned short* srcB = Bw + (size_t)(n0 + lrow) * 512 + sslot * 8;

  int offA[4], offB[4];
  #pragma unroll
  for (int mi = 0; mi < 4; ++mi) {
    int row = wr * 64 + mi * 16 + l15;
    offA[mi] = row * 64 + ((l4 ^ ((row >> 1) & 3)) * 16);
  }
  #pragma unroll
  for (int ni = 0; ni < 4; ++ni) {
    int row = wc * 64 + ni * 16 + l15;
    offB[ni] = 16384 + row * 64 + ((l4 ^ ((row >> 1) & 3)) * 16);
  }

  f32x4 acc[4][4];
  #pragma unroll
  for (int mi = 0; mi < 4; ++mi)
    #pragma unroll
    for (int ni = 0; ni < 4; ++ni)
      acc[mi][ni] = (f32x4){0.f, 0.f, 0.f, 0.f};

  // prologue: tiles 0 and 1 into buffers 0 and 1 (tile-grouped issue order)
  GLOAD_LDS16(srcA, ((char*)&AB[0][0]) + w * 1024);
  GLOAD_LDS16(srcB, ((char*)&AB[0][8192]) + w * 1024);
  GLOAD_LDS16(srcA + 32, ((char*)&AB[1][0]) + w * 1024);
  GLOAD_LDS16(srcB + 32, ((char*)&AB[1][8192]) + w * 1024);
  __builtin_amdgcn_sched_barrier(0);

  #pragma unroll
  for (int kt = 0; kt < 16; ++kt) {
    const int b = kt % 3;
    if (kt < 15) {
      asm volatile("s_waitcnt vmcnt(2)" ::: "memory");
    } else {
      asm volatile("s_waitcnt vmcnt(0)" ::: "memory");
    }
    __builtin_amdgcn_sched_barrier(0);
    __builtin_amdgcn_s_barrier();
    __builtin_amdgcn_sched_barrier(0);

    if (kt < 14) {
      const int k2 = (kt + 2) * 32;
      GLOAD_LDS16(srcA + k2, ((char*)&AB[(kt + 2) % 3][0]) + w * 1024);
      GLOAD_LDS16(srcB + k2, ((char*)&AB[(kt + 2) % 3][8192]) + w * 1024);
    }

    bf16x8 a[4], bv[4];
    #pragma unroll
    for (int mi = 0; mi < 4; ++mi)
      a[mi] = *(const bf16x8*)(((const char*)AB[b]) + offA[mi]);
    #pragma unroll
    for (int ni = 0; ni < 4; ++ni)
      bv[ni] = *(const bf16x8*)(((const char*)AB[b]) + offB[ni]);
    __builtin_amdgcn_s_setprio(1);
    #pragma unroll
    for (int mi = 0; mi < 4; ++mi)
      #pragma unroll
      for (int ni = 0; ni < 4; ++ni)
        acc[mi][ni] = __builtin_amdgcn_mfma_f32_16x16x32_bf16(a[mi], bv[ni], acc[mi][ni], 0, 0, 0);
    __builtin_amdgcn_s_setprio(0);
    __builtin_amdgcn_sched_barrier(0);
  }

  // epilogue: fused additive-attention partial score over 256 cols
  if (t < 256) {
    int gm = m0 + t;
    clds[t] = cl[gm < M ? gm : M - 1];
  }
  __syncthreads();
  #pragma unroll
  for (int mi = 0; mi < 4; ++mi) {
    #pragma unroll
    for (int r = 0; r < 4; ++r) {
      int rowt = wr * 64 + mi * 16 + l4 * 4 + r;
      int c = clds[rowt];
      const float* qrow = &qb[(size_t)c * 512];
      float s = 0.f;
      #pragma unroll
      for (int ni = 0; ni < 4; ++ni) {
        int gcol = n0 + wc * 64 + ni * 16 + l15;
        float x = acc[mi][ni][r] + qrow[gcol];
        s += tanh_fast(x) * Ws[gcol];
      }
      s += __shfl_xor(s, 1);
      s += __shfl_xor(s, 2);
      s += __shfl_xor(s, 4);
      s += __shfl_xor(s, 8);
      if (l15 == 0) red[rowt][wc] = s;
    }
  }
  __syncthreads();
  if (t < 256) {
    int gm = m0 + t;
    if (gm < M) atomicAdd(&out[gm], red[t][0] + red[t][1] + red[t][2] + red[t][3]);
  }
}

// --- bf16 MFMA GEMM: 128x128 tile, BK=32 -- small GEMMs only ---
template<int EPI>
__global__ __launch_bounds__(256)
void gemm128_k(const unsigned short* __restrict__ Abf,
               const unsigned short* __restrict__ Bw, int M,
               const float* __restrict__ bias, float* __restrict__ out)
{
  __shared__ unsigned short As[2][128 * 32];
  __shared__ unsigned short Bs[2][128 * 32];

  const int t = threadIdx.x;
  const int lane = t & 63;
  const int w = t >> 6;
  const int wr = w >> 1, wc = w & 1;
  const int l15 = lane & 15, l4 = lane >> 4;

  const int nwg = gridDim.x;
  int id = blockIdx.x;
  if ((nwg & 7) == 0) id = (id & 7) * (nwg >> 3) + (id >> 3);
  const int n0 = (id & 3) * 128;
  const int m0 = (id >> 2) * 128;

  const int rin = lane >> 2;
  const int sl = lane & 3;

  const unsigned short* srcA[2];
  const unsigned short* srcB[2];
  int dstOff[2];
  #pragma unroll
  for (int c = 0; c < 2; ++c) {
    int chunk = w * 2 + c;
    int row = chunk * 16 + rin;
    int slot = sl ^ ((row >> 1) & 3);
    int ga = m0 + row; if (ga > M - 1) ga = M - 1;
    srcA[c] = Abf + (size_t)ga * 512 + slot * 8;
    srcB[c] = Bw + (size_t)(n0 + row) * 512 + slot * 8;
    dstOff[c] = chunk * 1024;
  }

  int offA[4], offB[4];
  #pragma unroll
  for (int mi = 0; mi < 4; ++mi) {
    int row = wr * 64 + mi * 16 + l15;
    offA[mi] = row * 64 + ((l4 ^ ((row >> 1) & 3)) * 16);
  }
  #pragma unroll
  for (int ni = 0; ni < 4; ++ni) {
    int row = wc * 64 + ni * 16 + l15;
    offB[ni] = row * 64 + ((l4 ^ ((row >> 1) & 3)) * 16);
  }

  f32x4 acc[4][4];
  #pragma unroll
  for (int mi = 0; mi < 4; ++mi)
    #pragma unroll
    for (int ni = 0; ni < 4; ++ni)
      acc[mi][ni] = (f32x4){0.f, 0.f, 0.f, 0.f};

  #pragma unroll
  for (int c = 0; c < 2; ++c) {
    GLOAD_LDS16(srcA[c], ((char*)As[0]) + dstOff[c]);
    GLOAD_LDS16(srcB[c], ((char*)Bs[0]) + dstOff[c]);
  }
  __builtin_amdgcn_sched_barrier(0);

  #pragma unroll
  for (int it = 0; it < 16; ++it) {
    const int cur = it & 1;
    asm volatile("s_waitcnt vmcnt(0)" ::: "memory");
    __builtin_amdgcn_sched_barrier(0);
    __builtin_amdgcn_s_barrier();
    __builtin_amdgcn_sched_barrier(0);
    if (it < 15) {
      const int k1 = (it + 1) * 32;
      #pragma unroll
      for (int c = 0; c < 2; ++c) {
        GLOAD_LDS16(srcA[c] + k1, ((char*)As[cur ^ 1]) + dstOff[c]);
        GLOAD_LDS16(srcB[c] + k1, ((char*)Bs[cur ^ 1]) + dstOff[c]);
      }
    }
    {
      bf16x8 af[4], bfv[4];
      #pragma unroll
      for (int mi = 0; mi < 4; ++mi)
        af[mi] = *(const bf16x8*)(((const char*)As[cur]) + offA[mi]);
      #pragma unroll
      for (int ni = 0; ni < 4; ++ni)
        bfv[ni] = *(const bf16x8*)(((const char*)Bs[cur]) + offB[ni]);
      #pragma unroll
      for (int mi = 0; mi < 4; ++mi)
        #pragma unroll
        for (int ni = 0; ni < 4; ++ni)
          acc[mi][ni] = __builtin_amdgcn_mfma_f32_16x16x32_bf16(af[mi], bfv[ni], acc[mi][ni], 0, 0, 0);
    }
    __builtin_amdgcn_sched_barrier(0);
  }

  #pragma unroll
  for (int mi = 0; mi < 4; ++mi) {
    #pragma unroll
    for (int r = 0; r < 4; ++r) {
      int gm = m0 + wr * 64 + mi * 16 + l4 * 4 + r;
      if (gm < M) {
        #pragma unroll
        for (int ni = 0; ni < 4; ++ni) {
          int gcol = n0 + wc * 64 + ni * 16 + l15;
          float v = acc[mi][ni][r] + bias[gcol];
          if (EPI == 2) v = tanh_fast(v);
          out[(size_t)gm * 512 + gcol] = v;
        }
      }
    }
  }
}

// ---------------- host side ----------------

extern "C" void kernel_launch(void* const* d_in, const int* in_sizes, int n_in,
                              void* d_out, int out_size, void* d_ws, size_t ws_size,
                              hipStream_t stream) {
  const float* h  = (const float*)d_in[0];
  const float* g  = (const float*)d_in[1];
  const int*   vn = (const int*)d_in[2];
  const int*   nid= (const int*)d_in[3];
  const float* Wq = (const float*)d_in[4];
  const float* Wk = (const float*)d_in[5];
  const float* ab = (const float*)d_in[6];
  const float* Ws = (const float*)d_in[7];
  const float* W  = (const float*)d_in[9];
  const float* b  = (const float*)d_in[10];

  const int B = in_sizes[3];          // 100000
  const int C = in_sizes[1] / D_DIM;  // 1000

  char* wsb = (char*)d_ws;
  size_t off = 0;
  auto alloc = [&](size_t bytes) -> void* {
    void* p = wsb + off;
    off += (bytes + 255) & ~(size_t)255;
    return p;
  };

  unsigned short* hbf   = (unsigned short*)alloc((size_t)B * 512 * 2);
  unsigned short* gbf   = (unsigned short*)alloc((size_t)C * 512 * 2);
  unsigned short* ctxbf = (unsigned short*)alloc((size_t)C * 512 * 2);
  unsigned short* Wk_bf = (unsigned short*)alloc((size_t)512 * 512 * 2);  // contiguous
  unsigned short* Wq_bf = (unsigned short*)alloc((size_t)512 * 512 * 2);  // with Wk_bf
  unsigned short* W_bf  = (unsigned short*)alloc((size_t)512 * 512 * 2);  // and Wq_bf
  float* qb    = (float*)alloc((size_t)C * 512 * 4);
  float* ctx   = (float*)alloc((size_t)C * 512 * 4);
  float* score = (float*)alloc((size_t)B * 4);
  float* ev    = (float*)alloc((size_t)B * 4);
  int*   cl    = (int*)alloc((size_t)B * 4);
  int*   order = (int*)alloc((size_t)B * 4);
  int*      counts = (int*)alloc((size_t)C * 4);
  unsigned* smax   = (unsigned*)alloc((size_t)C * 4);
  float*    denom  = (float*)alloc((size_t)C * 4);
  int* starts = (int*)alloc((size_t)(C + 1) * 4);
  int* cursor = (int*)alloc((size_t)C * 4);
  (void)ws_size; (void)n_in; (void)out_size;

  size_t zlen = (size_t)((char*)denom - (char*)counts) + (size_t)C * 4;
  hipMemsetAsync(counts, 0, zlen, stream);
  hipMemsetAsync(score, 0, (size_t)B * 4, stream);

  // fused prologue: h/g/weights conversions + cluster-id gather/count
  {
    int nbH = (B * 128 + 255) / 256;
    int nbG = (C * 128 + 255) / 256;
    int nbW = 768;
    int nbP = (B + 255) / 256;
    prologue_k<<<nbH + nbG + nbW + nbP, 256, 0, stream>>>(
        h, g, Wk, Wq, W, vn, nid, hbf, gbf, Wk_bf, cl, counts, B, C);
  }

  prefix_k<<<1, 1024, 0, stream>>>(counts, starts, cursor, C);
  scatter_k<<<(B + 255) / 256, 256, 0, stream>>>(cl, cursor, order, B);

  // qb = g @ Wq^T + attn_bias
  gemm128_k<0><<<4 * ((C + 127) / 128), 256, 0, stream>>>(gbf, Wq_bf, C, ab, qb);

  // score[m] += per-256-col-block sum of tanh(h@Wk^T + qb[cl])·Ws
  // (bs dropped: softmax invariant to constant shift)
  gemm256sq_score_k<<<2 * ((B + 255) / 256), 1024, 0, stream>>>(
      hbf, Wk_bf, B, qb, cl, Ws, score);

  seg_max_k<<<(B + 255) / 256, 256, 0, stream>>>(score, cl, smax, B);
  seg_expsum_k<<<(B + 255) / 256, 256, 0, stream>>>(score, cl, smax, ev, denom, B);
  ctx_k<<<C, 256, 0, stream>>>(hbf, ev, order, starts, denom, ctx);

  cvt_f32_bf16_k<<<(C * 512 / 4 + 255) / 256, 256, 0, stream>>>(ctx, ctxbf, C * 512 / 4);

  // out = tanh(ctx @ W^T + b)
  gemm128_k<2><<<4 * ((C + 127) / 128), 256, 0, stream>>>(ctxbf, W_bf, C, b, (float*)d_out);
}

// Round 18
// 223.858 us; speedup vs baseline: 1.2243x; 1.0177x over previous
//
#include <hip/hip_runtime.h>
#include <stdint.h>

#define D_DIM 512

typedef __attribute__((ext_vector_type(8))) short bf16x8;
typedef __attribute__((ext_vector_type(4))) float f32x4;
typedef __attribute__((ext_vector_type(4))) short short4_t;
typedef __attribute__((ext_vector_type(4))) float float4_t;

__device__ __forceinline__ unsigned short f2bf(float f) {
  unsigned u = __float_as_uint(f);
  u += 0x7FFFu + ((u >> 16) & 1u);
  return (unsigned short)(u >> 16);
}

__device__ __forceinline__ float bf2f(unsigned short s) {
  return __uint_as_float(((unsigned)s) << 16);
}

__device__ __forceinline__ float tanh_fast(float x) {
  float e = __expf(2.0f * x);
  return 1.0f - 2.0f / (e + 1.0f);
}

#define GLOAD_LDS16(gsrc, ldst) \
  __builtin_amdgcn_global_load_lds((const __attribute__((address_space(1))) void*)(gsrc), \
                                   (__attribute__((address_space(3))) void*)(ldst), 16, 0, 0)

// ---------------- small utility kernels ----------------

__device__ __forceinline__ void cvt4_at(const float* __restrict__ in,
                                        unsigned short* __restrict__ out, int i) {
  float4_t v = ((const float4_t*)in)[i];
  short4_t s;
  s.x = (short)f2bf(v.x); s.y = (short)f2bf(v.y);
  s.z = (short)f2bf(v.z); s.w = (short)f2bf(v.w);
  ((short4_t*)out)[i] = s;
}

// FUSED prologue: h->bf16 (dominant, BW-bound) + g->bf16 + 3 weights->bf16 +
// prep_cluster, grid-partitioned. The small segments ride in the h-convert's shadow.
__global__ void prologue_k(const float* __restrict__ h, const float* __restrict__ g,
                           const float* __restrict__ Wk, const float* __restrict__ Wq,
                           const float* __restrict__ W,
                           const int* __restrict__ vn, const int* __restrict__ nid,
                           unsigned short* __restrict__ hbf, unsigned short* __restrict__ gbf,
                           unsigned short* __restrict__ Wbf3,  // Wk|Wq|W contiguous
                           int* __restrict__ cl, int* __restrict__ counts,
                           int B, int C) {
  const int n4h = B * 128;              // B*512/4
  const int n4g = C * 128;
  const int nbH = (n4h + 255) >> 8;
  const int nbG = (n4g + 255) >> 8;
  const int nbW = (3 * 65536 + 255) >> 8;   // 768
  int b = blockIdx.x;
  int t = threadIdx.x;
  if (b < nbH) {
    int i = b * 256 + t;
    if (i < n4h) cvt4_at(h, hbf, i);
  } else if (b < nbH + nbG) {
    int i = (b - nbH) * 256 + t;
    if (i < n4g) cvt4_at(g, gbf, i);
  } else if (b < nbH + nbG + nbW) {
    int i = (b - nbH - nbG) * 256 + t;  // < 196608
    int sel = i >> 16, j = i & 65535;   // 65536 f32x4 per weight matrix
    const float* src = (sel == 0) ? Wk : (sel == 1) ? Wq : W;
    float4_t v = ((const float4_t*)src)[j];
    short4_t s;
    s.x = (short)f2bf(v.x); s.y = (short)f2bf(v.y);
    s.z = (short)f2bf(v.z); s.w = (short)f2bf(v.w);
    ((short4_t*)Wbf3)[i] = s;
  } else {
    int i = (b - nbH - nbG - nbW) * 256 + t;
    if (i < B) {
      int c = vn[2 * nid[i] + 1];
      cl[i] = c;
      atomicAdd(&counts[c], 1);
    }
  }
}

__global__ void prefix_k(const int* __restrict__ counts, int* __restrict__ starts,
                         int* __restrict__ cursor, int C) {
  __shared__ int sh[1024];
  int t = threadIdx.x;
  int v = (t < C) ? counts[t] : 0;
  sh[t] = v;
  __syncthreads();
  for (int off = 1; off < 1024; off <<= 1) {
    int x = (t >= off) ? sh[t - off] : 0;
    __syncthreads();
    sh[t] += x;
    __syncthreads();
  }
  if (t < C) { int st = sh[t] - v; starts[t] = st; cursor[t] = st; }
  if (t == 1023) starts[C] = sh[1023];
}

__device__ __forceinline__ unsigned enc_f(float f) {
  unsigned u = __float_as_uint(f);
  return (u & 0x80000000u) ? ~u : (u | 0x80000000u);
}
__device__ __forceinline__ float dec_f(unsigned u) {
  return __uint_as_float((u & 0x80000000u) ? (u & 0x7FFFFFFFu) : ~u);
}

// FUSED: segment max (ordered-uint atomicMax) + counting-sort scatter.
// Legal: score and cursor are both final when this launches; writes independent.
__global__ void seg_max_scatter_k(const float* __restrict__ score, const int* __restrict__ cl,
                                  unsigned* __restrict__ smax, int* __restrict__ cursor,
                                  int* __restrict__ order, int B) {
  int i = blockIdx.x * blockDim.x + threadIdx.x;
  if (i < B) {
    int c = cl[i];
    atomicMax(&smax[c], enc_f(score[i]));
    int pos = atomicAdd(&cursor[c], 1);
    order[pos] = i;
  }
}

__global__ void seg_expsum_k(const float* __restrict__ score, const int* __restrict__ cl,
                             const unsigned* __restrict__ smax, float* __restrict__ ev,
                             float* __restrict__ denom, int B) {
  int i = blockIdx.x * blockDim.x + threadIdx.x;
  if (i < B) {
    int c = cl[i];
    float x = __expf(score[i] - dec_f(smax[c]));
    ev[i] = x;
    atomicAdd(&denom[c], x);
  }
}

// ctx_k now emits bf16 DIRECTLY (in-register f2bf before store): the separate
// ctx f32 buffer + cvt launch are gone.
__global__ __launch_bounds__(256)
void ctx_k(const unsigned short* __restrict__ hbf, const float* __restrict__ ev,
           const int* __restrict__ order, const int* __restrict__ starts,
           const float* __restrict__ denom, unsigned short* __restrict__ ctxbf) {
  int c = blockIdx.x;
  int t = threadIdx.x;
  int s0 = starts[c], s1 = starts[c + 1];
  float a0 = 0.f, a1 = 0.f;
  int j = s0;
  for (; j + 3 < s1; j += 4) {
    int i0 = order[j], i1 = order[j + 1], i2 = order[j + 2], i3 = order[j + 3];
    float e0 = ev[i0], e1 = ev[i1], e2 = ev[i2], e3 = ev[i3];
    unsigned u0 = *(const unsigned*)(hbf + (size_t)i0 * D_DIM + t * 2);
    unsigned u1 = *(const unsigned*)(hbf + (size_t)i1 * D_DIM + t * 2);
    unsigned u2 = *(const unsigned*)(hbf + (size_t)i2 * D_DIM + t * 2);
    unsigned u3 = *(const unsigned*)(hbf + (size_t)i3 * D_DIM + t * 2);
    a0 += e0 * bf2f((unsigned short)u0) + e1 * bf2f((unsigned short)u1)
        + e2 * bf2f((unsigned short)u2) + e3 * bf2f((unsigned short)u3);
    a1 += e0 * bf2f((unsigned short)(u0 >> 16)) + e1 * bf2f((unsigned short)(u1 >> 16))
        + e2 * bf2f((unsigned short)(u2 >> 16)) + e3 * bf2f((unsigned short)(u3 >> 16));
  }
  for (; j < s1; ++j) {
    int i0 = order[j];
    float e0 = ev[i0];
    unsigned u0 = *(const unsigned*)(hbf + (size_t)i0 * D_DIM + t * 2);
    a0 += e0 * bf2f((unsigned short)u0);
    a1 += e0 * bf2f((unsigned short)(u0 >> 16));
  }
  float inv = 1.0f / denom[c];
  unsigned r = ((unsigned)f2bf(a0 * inv)) | (((unsigned)f2bf(a1 * inv)) << 16);
  *(unsigned*)(&ctxbf[(size_t)c * D_DIM + t * 2]) = r;
}

// ====== 256x256 score GEMM, BK=32, TRIPLE-buffered depth-2 prefetch ======
// Session-best configuration (R11/R16/R17: ~130us, 0 bank conflicts, 0 spill).
__global__ __launch_bounds__(1024)
void gemm256sq_score_k(const unsigned short* __restrict__ Abf,
                       const unsigned short* __restrict__ Bw, int M,
                       const float* __restrict__ qb, const int* __restrict__ cl,
                       const float* __restrict__ Ws, float* __restrict__ out)
{
  __shared__ unsigned short AB[3][16384];
  __shared__ float red[256][4];
  __shared__ int clds[256];

  const int t = threadIdx.x;
  const int lane = t & 63;
  const int w = t >> 6;
  const int wr = w >> 2, wc = w & 3;
  const int l15 = lane & 15, l4 = lane >> 4;

  int id;
  {
    int nwg = gridDim.x;
    int q = nwg >> 3, r = nwg & 7;
    int xcd = blockIdx.x & 7, pos = blockIdx.x >> 3;
    id = (xcd < r ? xcd * (q + 1) : r * (q + 1) + (xcd - r) * q) + pos;
  }
  const int n0 = (id & 1) * 256;
  const int m0 = (id >> 1) * 256;

  const int rin = lane >> 2;
  const int lrow = w * 16 + rin;
  const int sslot = (lane & 3) ^ ((lrow >> 1) & 3);
  int rowA = m0 + lrow; if (rowA > M - 1) rowA = M - 1;
  const unsigned short* srcA = Abf + (size_t)rowA * 512 + sslot * 8;
  const unsigned short* srcB = Bw + (size_t)(n0 + lrow) * 512 + sslot * 8;

  int offA[4], offB[4];
  #pragma unroll
  for (int mi = 0; mi < 4; ++mi) {
    int row = wr * 64 + mi * 16 + l15;
    offA[mi] = row * 64 + ((l4 ^ ((row >> 1) & 3)) * 16);
  }
  #pragma unroll
  for (int ni = 0; ni < 4; ++ni) {
    int row = wc * 64 + ni * 16 + l15;
    offB[ni] = 16384 + row * 64 + ((l4 ^ ((row >> 1) & 3)) * 16);
  }

  f32x4 acc[4][4];
  #pragma unroll
  for (int mi = 0; mi < 4; ++mi)
    #pragma unroll
    for (int ni = 0; ni < 4; ++ni)
      acc[mi][ni] = (f32x4){0.f, 0.f, 0.f, 0.f};

  // prologue: tiles 0 and 1 into buffers 0 and 1 (tile-grouped issue order)
  GLOAD_LDS16(srcA, ((char*)&AB[0][0]) + w * 1024);
  GLOAD_LDS16(srcB, ((char*)&AB[0][8192]) + w * 1024);
  GLOAD_LDS16(srcA + 32, ((char*)&AB[1][0]) + w * 1024);
  GLOAD_LDS16(srcB + 32, ((char*)&AB[1][8192]) + w * 1024);
  __builtin_amdgcn_sched_barrier(0);

  #pragma unroll
  for (int kt = 0; kt < 16; ++kt) {
    const int b = kt % 3;
    if (kt < 15) {
      asm volatile("s_waitcnt vmcnt(2)" ::: "memory");
    } else {
      asm volatile("s_waitcnt vmcnt(0)" ::: "memory");
    }
    __builtin_amdgcn_sched_barrier(0);
    __builtin_amdgcn_s_barrier();
    __builtin_amdgcn_sched_barrier(0);

    if (kt < 14) {
      const int k2 = (kt + 2) * 32;
      GLOAD_LDS16(srcA + k2, ((char*)&AB[(kt + 2) % 3][0]) + w * 1024);
      GLOAD_LDS16(srcB + k2, ((char*)&AB[(kt + 2) % 3][8192]) + w * 1024);
    }

    bf16x8 a[4], bv[4];
    #pragma unroll
    for (int mi = 0; mi < 4; ++mi)
      a[mi] = *(const bf16x8*)(((const char*)AB[b]) + offA[mi]);
    #pragma unroll
    for (int ni = 0; ni < 4; ++ni)
      bv[ni] = *(const bf16x8*)(((const char*)AB[b]) + offB[ni]);
    __builtin_amdgcn_s_setprio(1);
    #pragma unroll
    for (int mi = 0; mi < 4; ++mi)
      #pragma unroll
      for (int ni = 0; ni < 4; ++ni)
        acc[mi][ni] = __builtin_amdgcn_mfma_f32_16x16x32_bf16(a[mi], bv[ni], acc[mi][ni], 0, 0, 0);
    __builtin_amdgcn_s_setprio(0);
    __builtin_amdgcn_sched_barrier(0);
  }

  // epilogue: fused additive-attention partial score over 256 cols
  if (t < 256) {
    int gm = m0 + t;
    clds[t] = cl[gm < M ? gm : M - 1];
  }
  __syncthreads();
  #pragma unroll
  for (int mi = 0; mi < 4; ++mi) {
    #pragma unroll
    for (int r = 0; r < 4; ++r) {
      int rowt = wr * 64 + mi * 16 + l4 * 4 + r;
      int c = clds[rowt];
      const float* qrow = &qb[(size_t)c * 512];
      float s = 0.f;
      #pragma unroll
      for (int ni = 0; ni < 4; ++ni) {
        int gcol = n0 + wc * 64 + ni * 16 + l15;
        float x = acc[mi][ni][r] + qrow[gcol];
        s += tanh_fast(x) * Ws[gcol];
      }
      s += __shfl_xor(s, 1);
      s += __shfl_xor(s, 2);
      s += __shfl_xor(s, 4);
      s += __shfl_xor(s, 8);
      if (l15 == 0) red[rowt][wc] = s;
    }
  }
  __syncthreads();
  if (t < 256) {
    int gm = m0 + t;
    if (gm < M) atomicAdd(&out[gm], red[t][0] + red[t][1] + red[t][2] + red[t][3]);
  }
}

// --- bf16 MFMA GEMM: 128x128 tile, BK=32 -- small GEMMs only ---
template<int EPI>
__global__ __launch_bounds__(256)
void gemm128_k(const unsigned short* __restrict__ Abf,
               const unsigned short* __restrict__ Bw, int M,
               const float* __restrict__ bias, float* __restrict__ out)
{
  __shared__ unsigned short As[2][128 * 32];
  __shared__ unsigned short Bs[2][128 * 32];

  const int t = threadIdx.x;
  const int lane = t & 63;
  const int w = t >> 6;
  const int wr = w >> 1, wc = w & 1;
  const int l15 = lane & 15, l4 = lane >> 4;

  const int nwg = gridDim.x;
  int id = blockIdx.x;
  if ((nwg & 7) == 0) id = (id & 7) * (nwg >> 3) + (id >> 3);
  const int n0 = (id & 3) * 128;
  const int m0 = (id >> 2) * 128;

  const int rin = lane >> 2;
  const int sl = lane & 3;

  const unsigned short* srcA[2];
  const unsigned short* srcB[2];
  int dstOff[2];
  #pragma unroll
  for (int c = 0; c < 2; ++c) {
    int chunk = w * 2 + c;
    int row = chunk * 16 + rin;
    int slot = sl ^ ((row >> 1) & 3);
    int ga = m0 + row; if (ga > M - 1) ga = M - 1;
    srcA[c] = Abf + (size_t)ga * 512 + slot * 8;
    srcB[c] = Bw + (size_t)(n0 + row) * 512 + slot * 8;
    dstOff[c] = chunk * 1024;
  }

  int offA[4], offB[4];
  #pragma unroll
  for (int mi = 0; mi < 4; ++mi) {
    int row = wr * 64 + mi * 16 + l15;
    offA[mi] = row * 64 + ((l4 ^ ((row >> 1) & 3)) * 16);
  }
  #pragma unroll
  for (int ni = 0; ni < 4; ++ni) {
    int row = wc * 64 + ni * 16 + l15;
    offB[ni] = row * 64 + ((l4 ^ ((row >> 1) & 3)) * 16);
  }

  f32x4 acc[4][4];
  #pragma unroll
  for (int mi = 0; mi < 4; ++mi)
    #pragma unroll
    for (int ni = 0; ni < 4; ++ni)
      acc[mi][ni] = (f32x4){0.f, 0.f, 0.f, 0.f};

  #pragma unroll
  for (int c = 0; c < 2; ++c) {
    GLOAD_LDS16(srcA[c], ((char*)As[0]) + dstOff[c]);
    GLOAD_LDS16(srcB[c], ((char*)Bs[0]) + dstOff[c]);
  }
  __builtin_amdgcn_sched_barrier(0);

  #pragma unroll
  for (int it = 0; it < 16; ++it) {
    const int cur = it & 1;
    asm volatile("s_waitcnt vmcnt(0)" ::: "memory");
    __builtin_amdgcn_sched_barrier(0);
    __builtin_amdgcn_s_barrier();
    __builtin_amdgcn_sched_barrier(0);
    if (it < 15) {
      const int k1 = (it + 1) * 32;
      #pragma unroll
      for (int c = 0; c < 2; ++c) {
        GLOAD_LDS16(srcA[c] + k1, ((char*)As[cur ^ 1]) + dstOff[c]);
        GLOAD_LDS16(srcB[c] + k1, ((char*)Bs[cur ^ 1]) + dstOff[c]);
      }
    }
    {
      bf16x8 af[4], bfv[4];
      #pragma unroll
      for (int mi = 0; mi < 4; ++mi)
        af[mi] = *(const bf16x8*)(((const char*)As[cur]) + offA[mi]);
      #pragma unroll
      for (int ni = 0; ni < 4; ++ni)
        bfv[ni] = *(const bf16x8*)(((const char*)Bs[cur]) + offB[ni]);
      #pragma unroll
      for (int mi = 0; mi < 4; ++mi)
        #pragma unroll
        for (int ni = 0; ni < 4; ++ni)
          acc[mi][ni] = __builtin_amdgcn_mfma_f32_16x16x32_bf16(af[mi], bfv[ni], acc[mi][ni], 0, 0, 0);
    }
    __builtin_amdgcn_sched_barrier(0);
  }

  #pragma unroll
  for (int mi = 0; mi < 4; ++mi) {
    #pragma unroll
    for (int r = 0; r < 4; ++r) {
      int gm = m0 + wr * 64 + mi * 16 + l4 * 4 + r;
      if (gm < M) {
        #pragma unroll
        for (int ni = 0; ni < 4; ++ni) {
          int gcol = n0 + wc * 64 + ni * 16 + l15;
          float v = acc[mi][ni][r] + bias[gcol];
          if (EPI == 2) v = tanh_fast(v);
          out[(size_t)gm * 512 + gcol] = v;
        }
      }
    }
  }
}

// ---------------- host side ----------------

extern "C" void kernel_launch(void* const* d_in, const int* in_sizes, int n_in,
                              void* d_out, int out_size, void* d_ws, size_t ws_size,
                              hipStream_t stream) {
  const float* h  = (const float*)d_in[0];
  const float* g  = (const float*)d_in[1];
  const int*   vn = (const int*)d_in[2];
  const int*   nid= (const int*)d_in[3];
  const float* Wq = (const float*)d_in[4];
  const float* Wk = (const float*)d_in[5];
  const float* ab = (const float*)d_in[6];
  const float* Ws = (const float*)d_in[7];
  const float* W  = (const float*)d_in[9];
  const float* b  = (const float*)d_in[10];

  const int B = in_sizes[3];          // 100000
  const int C = in_sizes[1] / D_DIM;  // 1000

  char* wsb = (char*)d_ws;
  size_t off = 0;
  auto alloc = [&](size_t bytes) -> void* {
    void* p = wsb + off;
    off += (bytes + 255) & ~(size_t)255;
    return p;
  };

  unsigned short* hbf   = (unsigned short*)alloc((size_t)B * 512 * 2);
  unsigned short* gbf   = (unsigned short*)alloc((size_t)C * 512 * 2);
  unsigned short* ctxbf = (unsigned short*)alloc((size_t)C * 512 * 2);
  unsigned short* Wk_bf = (unsigned short*)alloc((size_t)512 * 512 * 2);  // contiguous
  unsigned short* Wq_bf = (unsigned short*)alloc((size_t)512 * 512 * 2);  // with Wk_bf
  unsigned short* W_bf  = (unsigned short*)alloc((size_t)512 * 512 * 2);  // and Wq_bf
  float* qb    = (float*)alloc((size_t)C * 512 * 4);
  float* score = (float*)alloc((size_t)B * 4);
  float* ev    = (float*)alloc((size_t)B * 4);
  int*   cl    = (int*)alloc((size_t)B * 4);
  int*   order = (int*)alloc((size_t)B * 4);
  int*      counts = (int*)alloc((size_t)C * 4);
  unsigned* smax   = (unsigned*)alloc((size_t)C * 4);
  float*    denom  = (float*)alloc((size_t)C * 4);
  int* starts = (int*)alloc((size_t)(C + 1) * 4);
  int* cursor = (int*)alloc((size_t)C * 4);
  (void)ws_size; (void)n_in; (void)out_size;

  size_t zlen = (size_t)((char*)denom - (char*)counts) + (size_t)C * 4;
  hipMemsetAsync(counts, 0, zlen, stream);
  hipMemsetAsync(score, 0, (size_t)B * 4, stream);

  // fused prologue: h/g/weights conversions + cluster-id gather/count
  {
    int nbH = (B * 128 + 255) / 256;
    int nbG = (C * 128 + 255) / 256;
    int nbW = 768;
    int nbP = (B + 255) / 256;
    prologue_k<<<nbH + nbG + nbW + nbP, 256, 0, stream>>>(
        h, g, Wk, Wq, W, vn, nid, hbf, gbf, Wk_bf, cl, counts, B, C);
  }

  prefix_k<<<1, 1024, 0, stream>>>(counts, starts, cursor, C);

  // qb = g @ Wq^T + attn_bias
  gemm128_k<0><<<4 * ((C + 127) / 128), 256, 0, stream>>>(gbf, Wq_bf, C, ab, qb);

  // score[m] += per-256-col-block sum of tanh(h@Wk^T + qb[cl])·Ws
  // (bs dropped: softmax invariant to constant shift)
  gemm256sq_score_k<<<2 * ((B + 255) / 256), 1024, 0, stream>>>(
      hbf, Wk_bf, B, qb, cl, Ws, score);

  // fused segment-max + counting-sort scatter (one pass over B)
  seg_max_scatter_k<<<(B + 255) / 256, 256, 0, stream>>>(score, cl, smax, cursor, order, B);
  seg_expsum_k<<<(B + 255) / 256, 256, 0, stream>>>(score, cl, smax, ev, denom, B);
  ctx_k<<<C, 256, 0, stream>>>(hbf, ev, order, starts, denom, ctxbf);

  // out = tanh(ctx @ W^T + b)
  gemm128_k<2><<<4 * ((C + 127) / 128), 256, 0, stream>>>(ctxbf, W_bf, C, b, (float*)d_out);
}

// Round 19
// 216.981 us; speedup vs baseline: 1.2631x; 1.0317x over previous
//
#include <hip/hip_runtime.h>
#include <stdint.h>

#define D_DIM 512

typedef __attribute__((ext_vector_type(8))) short bf16x8;
typedef __attribute__((ext_vector_type(4))) float f32x4;
typedef __attribute__((ext_vector_type(4))) short short4_t;
typedef __attribute__((ext_vector_type(4))) float float4_t;

__device__ __forceinline__ unsigned short f2bf(float f) {
  unsigned u = __float_as_uint(f);
  u += 0x7FFFu + ((u >> 16) & 1u);
  return (unsigned short)(u >> 16);
}

__device__ __forceinline__ float bf2f(unsigned short s) {
  return __uint_as_float(((unsigned)s) << 16);
}

__device__ __forceinline__ float tanh_fast(float x) {
  float e = __expf(2.0f * x);
  return 1.0f - 2.0f / (e + 1.0f);
}

#define GLOAD_LDS16(gsrc, ldst) \
  __builtin_amdgcn_global_load_lds((const __attribute__((address_space(1))) void*)(gsrc), \
                                   (__attribute__((address_space(3))) void*)(ldst), 16, 0, 0)

// ---------------- small utility kernels ----------------

__device__ __forceinline__ void cvt4_at(const float* __restrict__ in,
                                        unsigned short* __restrict__ out, int i) {
  float4_t v = ((const float4_t*)in)[i];
  short4_t s;
  s.x = (short)f2bf(v.x); s.y = (short)f2bf(v.y);
  s.z = (short)f2bf(v.z); s.w = (short)f2bf(v.w);
  ((short4_t*)out)[i] = s;
}

// FUSED prologue: h->bf16 (dominant, BW-bound) + g->bf16 + 3 weights->bf16 +
// prep_cluster, grid-partitioned. The small segments ride in the h-convert's shadow.
__global__ void prologue_k(const float* __restrict__ h, const float* __restrict__ g,
                           const float* __restrict__ Wk, const float* __restrict__ Wq,
                           const float* __restrict__ W,
                           const int* __restrict__ vn, const int* __restrict__ nid,
                           unsigned short* __restrict__ hbf, unsigned short* __restrict__ gbf,
                           unsigned short* __restrict__ Wbf3,  // Wk|Wq|W contiguous
                           int* __restrict__ cl, int* __restrict__ counts,
                           int B, int C) {
  const int n4h = B * 128;              // B*512/4
  const int n4g = C * 128;
  const int nbH = (n4h + 255) >> 8;
  const int nbG = (n4g + 255) >> 8;
  const int nbW = (3 * 65536 + 255) >> 8;   // 768
  int b = blockIdx.x;
  int t = threadIdx.x;
  if (b < nbH) {
    int i = b * 256 + t;
    if (i < n4h) cvt4_at(h, hbf, i);
  } else if (b < nbH + nbG) {
    int i = (b - nbH) * 256 + t;
    if (i < n4g) cvt4_at(g, gbf, i);
  } else if (b < nbH + nbG + nbW) {
    int i = (b - nbH - nbG) * 256 + t;  // < 196608
    int sel = i >> 16, j = i & 65535;   // 65536 f32x4 per weight matrix
    const float* src = (sel == 0) ? Wk : (sel == 1) ? Wq : W;
    float4_t v = ((const float4_t*)src)[j];
    short4_t s;
    s.x = (short)f2bf(v.x); s.y = (short)f2bf(v.y);
    s.z = (short)f2bf(v.z); s.w = (short)f2bf(v.w);
    ((short4_t*)Wbf3)[i] = s;
  } else {
    int i = (b - nbH - nbG - nbW) * 256 + t;
    if (i < B) {
      int c = vn[2 * nid[i] + 1];
      cl[i] = c;
      atomicAdd(&counts[c], 1);
    }
  }
}

__global__ void prefix_k(const int* __restrict__ counts, int* __restrict__ starts,
                         int* __restrict__ cursor, int C) {
  __shared__ int sh[1024];
  int t = threadIdx.x;
  int v = (t < C) ? counts[t] : 0;
  sh[t] = v;
  __syncthreads();
  for (int off = 1; off < 1024; off <<= 1) {
    int x = (t >= off) ? sh[t - off] : 0;
    __syncthreads();
    sh[t] += x;
    __syncthreads();
  }
  if (t < C) { int st = sh[t] - v; starts[t] = st; cursor[t] = st; }
  if (t == 1023) starts[C] = sh[1023];
}

__device__ __forceinline__ unsigned enc_f(float f) {
  unsigned u = __float_as_uint(f);
  return (u & 0x80000000u) ? ~u : (u | 0x80000000u);
}
__device__ __forceinline__ float dec_f(unsigned u) {
  return __uint_as_float((u & 0x80000000u) ? (u & 0x7FFFFFFFu) : ~u);
}

// FUSED: segment max (ordered-uint atomicMax) + counting-sort scatter.
__global__ void seg_max_scatter_k(const float* __restrict__ score, const int* __restrict__ cl,
                                  unsigned* __restrict__ smax, int* __restrict__ cursor,
                                  int* __restrict__ order, int B) {
  int i = blockIdx.x * blockDim.x + threadIdx.x;
  if (i < B) {
    int c = cl[i];
    atomicMax(&smax[c], enc_f(score[i]));
    int pos = atomicAdd(&cursor[c], 1);
    order[pos] = i;
  }
}

// ctx_k with FUSED exp + denominator: reads score+smax directly, computes
// e = exp(score - smax[c]) inline (each thread redundantly -- v_exp cost is
// negligible vs the gathered-row memory latency it hides under) and accumulates
// the denominator locally in the same pass. Replaces seg_expsum + ev + denom.
// Emits bf16 directly.
__global__ __launch_bounds__(256)
void ctx_k(const unsigned short* __restrict__ hbf, const float* __restrict__ score,
           const int* __restrict__ order, const int* __restrict__ starts,
           const unsigned* __restrict__ smax, unsigned short* __restrict__ ctxbf) {
  int c = blockIdx.x;
  int t = threadIdx.x;
  int s0 = starts[c], s1 = starts[c + 1];
  float m = dec_f(smax[c]);
  float a0 = 0.f, a1 = 0.f, den = 0.f;
  int j = s0;
  for (; j + 3 < s1; j += 4) {
    int i0 = order[j], i1 = order[j + 1], i2 = order[j + 2], i3 = order[j + 3];
    float e0 = __expf(score[i0] - m), e1 = __expf(score[i1] - m);
    float e2 = __expf(score[i2] - m), e3 = __expf(score[i3] - m);
    unsigned u0 = *(const unsigned*)(hbf + (size_t)i0 * D_DIM + t * 2);
    unsigned u1 = *(const unsigned*)(hbf + (size_t)i1 * D_DIM + t * 2);
    unsigned u2 = *(const unsigned*)(hbf + (size_t)i2 * D_DIM + t * 2);
    unsigned u3 = *(const unsigned*)(hbf + (size_t)i3 * D_DIM + t * 2);
    a0 += e0 * bf2f((unsigned short)u0) + e1 * bf2f((unsigned short)u1)
        + e2 * bf2f((unsigned short)u2) + e3 * bf2f((unsigned short)u3);
    a1 += e0 * bf2f((unsigned short)(u0 >> 16)) + e1 * bf2f((unsigned short)(u1 >> 16))
        + e2 * bf2f((unsigned short)(u2 >> 16)) + e3 * bf2f((unsigned short)(u3 >> 16));
    den += (e0 + e1) + (e2 + e3);
  }
  for (; j < s1; ++j) {
    int i0 = order[j];
    float e0 = __expf(score[i0] - m);
    unsigned u0 = *(const unsigned*)(hbf + (size_t)i0 * D_DIM + t * 2);
    a0 += e0 * bf2f((unsigned short)u0);
    a1 += e0 * bf2f((unsigned short)(u0 >> 16));
    den += e0;
  }
  float inv = 1.0f / den;
  unsigned r = ((unsigned)f2bf(a0 * inv)) | (((unsigned)f2bf(a1 * inv)) << 16);
  *(unsigned*)(&ctxbf[(size_t)c * D_DIM + t * 2]) = r;
}

// ====== 256x256 score GEMM, BK=32, TRIPLE-buffered depth-2 prefetch ======
// Session-best configuration (R11/R16-R18: ~130us, 0 bank conflicts, 0 spill).
__global__ __launch_bounds__(1024)
void gemm256sq_score_k(const unsigned short* __restrict__ Abf,
                       const unsigned short* __restrict__ Bw, int M,
                       const float* __restrict__ qb, const int* __restrict__ cl,
                       const float* __restrict__ Ws, float* __restrict__ out)
{
  __shared__ unsigned short AB[3][16384];
  __shared__ float red[256][4];
  __shared__ int clds[256];

  const int t = threadIdx.x;
  const int lane = t & 63;
  const int w = t >> 6;
  const int wr = w >> 2, wc = w & 3;
  const int l15 = lane & 15, l4 = lane >> 4;

  int id;
  {
    int nwg = gridDim.x;
    int q = nwg >> 3, r = nwg & 7;
    int xcd = blockIdx.x & 7, pos = blockIdx.x >> 3;
    id = (xcd < r ? xcd * (q + 1) : r * (q + 1) + (xcd - r) * q) + pos;
  }
  const int n0 = (id & 1) * 256;
  const int m0 = (id >> 1) * 256;

  const int rin = lane >> 2;
  const int lrow = w * 16 + rin;
  const int sslot = (lane & 3) ^ ((lrow >> 1) & 3);
  int rowA = m0 + lrow; if (rowA > M - 1) rowA = M - 1;
  const unsigned short* srcA = Abf + (size_t)rowA * 512 + sslot * 8;
  const unsigned short* srcB = Bw + (size_t)(n0 + lrow) * 512 + sslot * 8;

  int offA[4], offB[4];
  #pragma unroll
  for (int mi = 0; mi < 4; ++mi) {
    int row = wr * 64 + mi * 16 + l15;
    offA[mi] = row * 64 + ((l4 ^ ((row >> 1) & 3)) * 16);
  }
  #pragma unroll
  for (int ni = 0; ni < 4; ++ni) {
    int row = wc * 64 + ni * 16 + l15;
    offB[ni] = 16384 + row * 64 + ((l4 ^ ((row >> 1) & 3)) * 16);
  }

  f32x4 acc[4][4];
  #pragma unroll
  for (int mi = 0; mi < 4; ++mi)
    #pragma unroll
    for (int ni = 0; ni < 4; ++ni)
      acc[mi][ni] = (f32x4){0.f, 0.f, 0.f, 0.f};

  // prologue: tiles 0 and 1 into buffers 0 and 1 (tile-grouped issue order)
  GLOAD_LDS16(srcA, ((char*)&AB[0][0]) + w * 1024);
  GLOAD_LDS16(srcB, ((char*)&AB[0][8192]) + w * 1024);
  GLOAD_LDS16(srcA + 32, ((char*)&AB[1][0]) + w * 1024);
  GLOAD_LDS16(srcB + 32, ((char*)&AB[1][8192]) + w * 1024);
  __builtin_amdgcn_sched_barrier(0);

  #pragma unroll
  for (int kt = 0; kt < 16; ++kt) {
    const int b = kt % 3;
    if (kt < 15) {
      asm volatile("s_waitcnt vmcnt(2)" ::: "memory");
    } else {
      asm volatile("s_waitcnt vmcnt(0)" ::: "memory");
    }
    __builtin_amdgcn_sched_barrier(0);
    __builtin_amdgcn_s_barrier();
    __builtin_amdgcn_sched_barrier(0);

    if (kt < 14) {
      const int k2 = (kt + 2) * 32;
      GLOAD_LDS16(srcA + k2, ((char*)&AB[(kt + 2) % 3][0]) + w * 1024);
      GLOAD_LDS16(srcB + k2, ((char*)&AB[(kt + 2) % 3][8192]) + w * 1024);
    }

    bf16x8 a[4], bv[4];
    #pragma unroll
    for (int mi = 0; mi < 4; ++mi)
      a[mi] = *(const bf16x8*)(((const char*)AB[b]) + offA[mi]);
    #pragma unroll
    for (int ni = 0; ni < 4; ++ni)
      bv[ni] = *(const bf16x8*)(((const char*)AB[b]) + offB[ni]);
    __builtin_amdgcn_s_setprio(1);
    #pragma unroll
    for (int mi = 0; mi < 4; ++mi)
      #pragma unroll
      for (int ni = 0; ni < 4; ++ni)
        acc[mi][ni] = __builtin_amdgcn_mfma_f32_16x16x32_bf16(a[mi], bv[ni], acc[mi][ni], 0, 0, 0);
    __builtin_amdgcn_s_setprio(0);
    __builtin_amdgcn_sched_barrier(0);
  }

  // epilogue: fused additive-attention partial score over 256 cols
  if (t < 256) {
    int gm = m0 + t;
    clds[t] = cl[gm < M ? gm : M - 1];
  }
  __syncthreads();
  #pragma unroll
  for (int mi = 0; mi < 4; ++mi) {
    #pragma unroll
    for (int r = 0; r < 4; ++r) {
      int rowt = wr * 64 + mi * 16 + l4 * 4 + r;
      int c = clds[rowt];
      const float* qrow = &qb[(size_t)c * 512];
      float s = 0.f;
      #pragma unroll
      for (int ni = 0; ni < 4; ++ni) {
        int gcol = n0 + wc * 64 + ni * 16 + l15;
        float x = acc[mi][ni][r] + qrow[gcol];
        s += tanh_fast(x) * Ws[gcol];
      }
      s += __shfl_xor(s, 1);
      s += __shfl_xor(s, 2);
      s += __shfl_xor(s, 4);
      s += __shfl_xor(s, 8);
      if (l15 == 0) red[rowt][wc] = s;
    }
  }
  __syncthreads();
  if (t < 256) {
    int gm = m0 + t;
    if (gm < M) atomicAdd(&out[gm], red[t][0] + red[t][1] + red[t][2] + red[t][3]);
  }
}

// --- bf16 MFMA GEMM: 128x128 tile, BK=32 -- small GEMMs only ---
template<int EPI>
__global__ __launch_bounds__(256)
void gemm128_k(const unsigned short* __restrict__ Abf,
               const unsigned short* __restrict__ Bw, int M,
               const float* __restrict__ bias, float* __restrict__ out)
{
  __shared__ unsigned short As[2][128 * 32];
  __shared__ unsigned short Bs[2][128 * 32];

  const int t = threadIdx.x;
  const int lane = t & 63;
  const int w = t >> 6;
  const int wr = w >> 1, wc = w & 1;
  const int l15 = lane & 15, l4 = lane >> 4;

  const int nwg = gridDim.x;
  int id = blockIdx.x;
  if ((nwg & 7) == 0) id = (id & 7) * (nwg >> 3) + (id >> 3);
  const int n0 = (id & 3) * 128;
  const int m0 = (id >> 2) * 128;

  const int rin = lane >> 2;
  const int sl = lane & 3;

  const unsigned short* srcA[2];
  const unsigned short* srcB[2];
  int dstOff[2];
  #pragma unroll
  for (int c = 0; c < 2; ++c) {
    int chunk = w * 2 + c;
    int row = chunk * 16 + rin;
    int slot = sl ^ ((row >> 1) & 3);
    int ga = m0 + row; if (ga > M - 1) ga = M - 1;
    srcA[c] = Abf + (size_t)ga * 512 + slot * 8;
    srcB[c] = Bw + (size_t)(n0 + row) * 512 + slot * 8;
    dstOff[c] = chunk * 1024;
  }

  int offA[4], offB[4];
  #pragma unroll
  for (int mi = 0; mi < 4; ++mi) {
    int row = wr * 64 + mi * 16 + l15;
    offA[mi] = row * 64 + ((l4 ^ ((row >> 1) & 3)) * 16);
  }
  #pragma unroll
  for (int ni = 0; ni < 4; ++ni) {
    int row = wc * 64 + ni * 16 + l15;
    offB[ni] = row * 64 + ((l4 ^ ((row >> 1) & 3)) * 16);
  }

  f32x4 acc[4][4];
  #pragma unroll
  for (int mi = 0; mi < 4; ++mi)
    #pragma unroll
    for (int ni = 0; ni < 4; ++ni)
      acc[mi][ni] = (f32x4){0.f, 0.f, 0.f, 0.f};

  #pragma unroll
  for (int c = 0; c < 2; ++c) {
    GLOAD_LDS16(srcA[c], ((char*)As[0]) + dstOff[c]);
    GLOAD_LDS16(srcB[c], ((char*)Bs[0]) + dstOff[c]);
  }
  __builtin_amdgcn_sched_barrier(0);

  #pragma unroll
  for (int it = 0; it < 16; ++it) {
    const int cur = it & 1;
    asm volatile("s_waitcnt vmcnt(0)" ::: "memory");
    __builtin_amdgcn_sched_barrier(0);
    __builtin_amdgcn_s_barrier();
    __builtin_amdgcn_sched_barrier(0);
    if (it < 15) {
      const int k1 = (it + 1) * 32;
      #pragma unroll
      for (int c = 0; c < 2; ++c) {
        GLOAD_LDS16(srcA[c] + k1, ((char*)As[cur ^ 1]) + dstOff[c]);
        GLOAD_LDS16(srcB[c] + k1, ((char*)Bs[cur ^ 1]) + dstOff[c]);
      }
    }
    {
      bf16x8 af[4], bfv[4];
      #pragma unroll
      for (int mi = 0; mi < 4; ++mi)
        af[mi] = *(const bf16x8*)(((const char*)As[cur]) + offA[mi]);
      #pragma unroll
      for (int ni = 0; ni < 4; ++ni)
        bfv[ni] = *(const bf16x8*)(((const char*)Bs[cur]) + offB[ni]);
      #pragma unroll
      for (int mi = 0; mi < 4; ++mi)
        #pragma unroll
        for (int ni = 0; ni < 4; ++ni)
          acc[mi][ni] = __builtin_amdgcn_mfma_f32_16x16x32_bf16(af[mi], bfv[ni], acc[mi][ni], 0, 0, 0);
    }
    __builtin_amdgcn_sched_barrier(0);
  }

  #pragma unroll
  for (int mi = 0; mi < 4; ++mi) {
    #pragma unroll
    for (int r = 0; r < 4; ++r) {
      int gm = m0 + wr * 64 + mi * 16 + l4 * 4 + r;
      if (gm < M) {
        #pragma unroll
        for (int ni = 0; ni < 4; ++ni) {
          int gcol = n0 + wc * 64 + ni * 16 + l15;
          float v = acc[mi][ni][r] + bias[gcol];
          if (EPI == 2) v = tanh_fast(v);
          out[(size_t)gm * 512 + gcol] = v;
        }
      }
    }
  }
}

// ---------------- host side ----------------

extern "C" void kernel_launch(void* const* d_in, const int* in_sizes, int n_in,
                              void* d_out, int out_size, void* d_ws, size_t ws_size,
                              hipStream_t stream) {
  const float* h  = (const float*)d_in[0];
  const float* g  = (const float*)d_in[1];
  const int*   vn = (const int*)d_in[2];
  const int*   nid= (const int*)d_in[3];
  const float* Wq = (const float*)d_in[4];
  const float* Wk = (const float*)d_in[5];
  const float* ab = (const float*)d_in[6];
  const float* Ws = (const float*)d_in[7];
  const float* W  = (const float*)d_in[9];
  const float* b  = (const float*)d_in[10];

  const int B = in_sizes[3];          // 100000
  const int C = in_sizes[1] / D_DIM;  // 1000

  char* wsb = (char*)d_ws;
  size_t off = 0;
  auto alloc = [&](size_t bytes) -> void* {
    void* p = wsb + off;
    off += (bytes + 255) & ~(size_t)255;
    return p;
  };

  unsigned short* hbf   = (unsigned short*)alloc((size_t)B * 512 * 2);
  unsigned short* gbf   = (unsigned short*)alloc((size_t)C * 512 * 2);
  unsigned short* ctxbf = (unsigned short*)alloc((size_t)C * 512 * 2);
  unsigned short* Wk_bf = (unsigned short*)alloc((size_t)512 * 512 * 2);  // contiguous
  unsigned short* Wq_bf = (unsigned short*)alloc((size_t)512 * 512 * 2);  // with Wk_bf
  unsigned short* W_bf  = (unsigned short*)alloc((size_t)512 * 512 * 2);  // and Wq_bf
  float* qb    = (float*)alloc((size_t)C * 512 * 4);
  float* score = (float*)alloc((size_t)B * 4);
  int*   cl    = (int*)alloc((size_t)B * 4);
  int*   order = (int*)alloc((size_t)B * 4);
  int*      counts = (int*)alloc((size_t)C * 4);
  unsigned* smax   = (unsigned*)alloc((size_t)C * 4);
  int* starts = (int*)alloc((size_t)(C + 1) * 4);
  int* cursor = (int*)alloc((size_t)C * 4);
  (void)ws_size; (void)n_in; (void)out_size;

  // zero counts + smax (contiguous); smax=0 encodes -inf under enc_f ordering
  size_t zlen = (size_t)((char*)smax - (char*)counts) + (size_t)C * 4;
  hipMemsetAsync(counts, 0, zlen, stream);
  hipMemsetAsync(score, 0, (size_t)B * 4, stream);

  // fused prologue: h/g/weights conversions + cluster-id gather/count
  {
    int nbH = (B * 128 + 255) / 256;
    int nbG = (C * 128 + 255) / 256;
    int nbW = 768;
    int nbP = (B + 255) / 256;
    prologue_k<<<nbH + nbG + nbW + nbP, 256, 0, stream>>>(
        h, g, Wk, Wq, W, vn, nid, hbf, gbf, Wk_bf, cl, counts, B, C);
  }

  prefix_k<<<1, 1024, 0, stream>>>(counts, starts, cursor, C);

  // qb = g @ Wq^T + attn_bias
  gemm128_k<0><<<4 * ((C + 127) / 128), 256, 0, stream>>>(gbf, Wq_bf, C, ab, qb);

  // score[m] += per-256-col-block sum of tanh(h@Wk^T + qb[cl])·Ws
  // (bs dropped: softmax invariant to constant shift)
  gemm256sq_score_k<<<2 * ((B + 255) / 256), 1024, 0, stream>>>(
      hbf, Wk_bf, B, qb, cl, Ws, score);

  // fused segment-max + counting-sort scatter (one pass over B)
  seg_max_scatter_k<<<(B + 255) / 256, 256, 0, stream>>>(score, cl, smax, cursor, order, B);

  // ctx with fused exp + local denominator (replaces seg_expsum + ev + denom)
  ctx_k<<<C, 256, 0, stream>>>(hbf, score, order, starts, smax, ctxbf);

  // out = tanh(ctx @ W^T + b)
  gemm128_k<2><<<4 * ((C + 127) / 128), 256, 0, stream>>>(ctxbf, W_bf, C, b, (float*)d_out);
}